// Round 7
// baseline (1084.215 us; speedup 1.0000x reference)
//
#include <hip/hip_runtime.h>
#include <stdint.h>

typedef unsigned short u16;
typedef unsigned int u32;
typedef __attribute__((ext_vector_type(8))) __bf16 bf16x8;
typedef __attribute__((ext_vector_type(4))) float f32x4;

#define DEVINL __device__ __forceinline__

DEVINL float bf2f(u16 u){ union{u32 i; float f;} c; c.i = ((u32)u)<<16; return c.f; }
DEVINL u16 f2bf(float f){ union{float f; u32 i;} c; c.f=f; u32 u=c.i; return (u16)((u + 0x7fffu + ((u>>16)&1u))>>16); }
DEVINL u32 pack2(float a, float b){ return (u32)f2bf(a) | ((u32)f2bf(b)<<16); }
DEVINL float sq2(u32 u){ float a = bf2f((u16)(u&0xffffu)), b = bf2f((u16)(u>>16)); return a*a + b*b; }

// parity of sign(e_a * e_b) in Cl(4,1): reorder swaps + metric (e4^2 = -1)
DEVINL int sign_neg(int a, int b){
  int s = __popc((a>>1)&b) + __popc((a>>2)&b) + __popc((a>>3)&b) + __popc((a>>4)&b) + ((a&b)>>4);
  return s & 1;
}

DEVINL void gload_lds16(const void* g, void* l){
  __builtin_amdgcn_global_load_lds(
    (const __attribute__((address_space(1))) void*)g,
    (__attribute__((address_space(3))) void*)l, 16, 0, 0);
}

// ---------------- transpose x: [bs][i=256][n=32] f32 -> xt [bs*32+n][i] bf16 -----
__global__ __launch_bounds__(256) void k_tr_x(const float* __restrict__ x, u16* __restrict__ xt){
  __shared__ float tile[256][33];
  const int bs = blockIdx.x, t = threadIdx.x;
  const float* xp = x + (size_t)bs*8192 + t*32;
  #pragma unroll
  for (int n=0;n<32;n+=4){
    float4 v = *(const float4*)(xp + n);
    tile[t][n]=v.x; tile[t][n+1]=v.y; tile[t][n+2]=v.z; tile[t][n+3]=v.w;
  }
  __syncthreads();
  const int n = t>>3, i0 = (t&7)*32;
  u16* dst = xt + ((size_t)bs*32 + n)*256 + i0;
  #pragma unroll
  for (int q=0;q<4;q++){
    u32 w0 = pack2(tile[i0+q*8+0][n], tile[i0+q*8+1][n]);
    u32 w1 = pack2(tile[i0+q*8+2][n], tile[i0+q*8+3][n]);
    u32 w2 = pack2(tile[i0+q*8+4][n], tile[i0+q*8+5][n]);
    u32 w3 = pack2(tile[i0+q*8+6][n], tile[i0+q*8+7][n]);
    *(uint4*)(dst + q*8) = make_uint4(w0,w1,w2,w3);
  }
}

// ---------------- transpose w: w[o][i][m] f32 -> wT[wsel][m][o][i] bf16 ----------
__global__ __launch_bounds__(256) void k_tr_w(const float* __restrict__ wq, const float* __restrict__ wk,
                                              const float* __restrict__ wv, const float* __restrict__ wo,
                                              u16* __restrict__ wT){
  __shared__ float tile[256][33];
  const int bid = blockIdx.x, t = threadIdx.x;
  const int wsel = bid>>8, o = bid&255;
  const float* w = wsel==0?wq: wsel==1?wk: wsel==2?wv: wo;
  const float* wp = w + ((size_t)o*256 + t)*32;
  #pragma unroll
  for (int m=0;m<32;m+=4){
    float4 v = *(const float4*)(wp + m);
    tile[t][m]=v.x; tile[t][m+1]=v.y; tile[t][m+2]=v.z; tile[t][m+3]=v.w;
  }
  __syncthreads();
  const int m = t>>3, i0 = (t&7)*32;
  u16* dst = wT + (((size_t)wsel*32 + m)*256 + o)*256 + i0;
  #pragma unroll
  for (int q=0;q<4;q++){
    u32 w0 = pack2(tile[i0+q*8+0][m], tile[i0+q*8+1][m]);
    u32 w1 = pack2(tile[i0+q*8+2][m], tile[i0+q*8+3][m]);
    u32 w2 = pack2(tile[i0+q*8+4][m], tile[i0+q*8+5][m]);
    u32 w3 = pack2(tile[i0+q*8+6][m], tile[i0+q*8+7][m]);
    *(uint4*)(dst + q*8) = make_uint4(w0,w1,w2,w3);
  }
}

// ---- geo GEMM building blocks: A in LDS (reused 32x per m), B streamed to regs ----
DEVINL void geo_loadB(const u16* __restrict__ bp, const int (&boff)[4], uint4 (&Br)[8]){
  #pragma unroll
  for (int f=0; f<4; ++f){
    Br[f*2+0] = *(const uint4*)(bp + boff[f]);
    Br[f*2+1] = *(const uint4*)(bp + boff[f] + 32);
  }
}

DEVINL void geo_compute(int m, u32 smask, const u16* __restrict__ Apan,
                        const uint4 (&Br)[8], f32x4 (&acc)[4][4],
                        const int (&raLo)[4], const int (&raHi)[4], int hi){
  #pragma unroll
  for (int kk=0; kk<2; ++kk){
    bf16x8 af[4];
    #pragma unroll
    for (int f=0; f<4; ++f){
      const int rowx = raLo[f] ^ m;
      const int rr = raHi[f] | rowx;
      const u32 sx = ((smask >> rowx) & 1u) ? 0x80008000u : 0u;
      uint4 av = *(const uint4*)(Apan + rr*64 + (((kk*4+hi) ^ (rr&7))*8));
      av.x^=sx; av.y^=sx; av.z^=sx; av.w^=sx;
      af[f] = *(const bf16x8*)&av;
    }
    __builtin_amdgcn_s_setprio(1);
    #pragma unroll
    for (int fm=0; fm<4; ++fm){
      #pragma unroll
      for (int fn=0; fn<4; ++fn)
        acc[fm][fn] = __builtin_amdgcn_mfma_f32_16x16x32_bf16(
            af[fm], *(const bf16x8*)&Br[fn*2+kk], acc[fm][fn], 0,0,0);
    }
    __builtin_amdgcn_s_setprio(0);
  }
}

// geo GEMM: out[bs,o,l] = sum_{m,i} xt[bs,l^m,i]*sign(m,l^m)*wT[m][o][i]
// 128x128 tile, 4 waves (2x2). A i-quarter LDS-resident (16 KB, staged 4x);
// per-m blade perm+sign at fragment read. B global->register streaming with
// named 2-buffer prefetch; NO barriers inside the m-loop.
template<int EPI>
__global__ __launch_bounds__(256) void k_geo_gemm(const u16* __restrict__ xt, const u16* __restrict__ wT,
                                                  u16* __restrict__ qkv, float* __restrict__ dout){
  constexpr int NT = (EPI==0)?6:2;
  constexpr int NWG = 256*NT;
  __shared__ __align__(16) u16 Apan[128*64];     // 16 KB
  __shared__ u32 SGN[32];
  const int wg = blockIdx.x;
  const int bid = (wg&7)*(NWG/8) + (wg>>3);      // bijective XCD chunking
  const int tn = bid >> 8;                        // tn-major: 1 B panel per XCD (L2-fit)
  const int tm = bid & 255;
  const int row0 = tm*128, col0 = tn*128;
  const int wsel = (EPI==0)? (col0>>8) : 3;
  const int o0   = (EPI==0)? (col0&255) : col0;
  const u16* wp = wT + (size_t)wsel*32*256*256;
  const int t = threadIdx.x, lane = t&63, wid = t>>6;
  const int wm = wid>>1, wn = wid&1, lo = lane&15, hi = lane>>4;

  if (t < 32){
    u32 msk = 0;
    #pragma unroll
    for (int n=0;n<32;n++) msk |= (u32)sign_neg(t,n) << n;
    SGN[t] = msk;
  }

  int raLo[4], raHi[4], boff[4];
  #pragma unroll
  for (int f=0; f<4; ++f){
    const int ra = wm*64 + f*16 + lo;
    raLo[f] = ra & 31; raHi[f] = ra & 96;
    boff[f] = (o0 + wn*64 + f*16 + lo)*256 + hi*8;
  }

  f32x4 acc[4][4];
  #pragma unroll
  for(int a=0;a<4;a++){
    #pragma unroll
    for(int b=0;b<4;b++){ acc[a][b] = (f32x4){0.f,0.f,0.f,0.f}; }
  }

  for (int q=0; q<4; ++q){
    __syncthreads();                 // readers of previous Apan done (also orders SGN init)
    #pragma unroll
    for (int c=0;c<4;c++){
      const int base = (wid*4+c)*64;
      const int idxA = base + lane;
      const int rrs = idxA>>3, g = idxA&7;
      gload_lds16(xt + (size_t)(row0+rrs)*256 + q*64 + ((g^(rrs&7))*8), Apan + base*8);
    }
    __syncthreads();                 // compiler drains vmcnt before barrier -> A visible
    const u16* wq_ = wp + q*64;
    uint4 Ba[8], Bb[8];
    geo_loadB(wq_ + 0*65536, boff, Ba);
    geo_loadB(wq_ + 1*65536, boff, Bb);
    #pragma unroll 1
    for (int mm=0; mm<16; ++mm){
      const int m0 = 2*mm, m1 = m0+1;
      geo_compute(m0, SGN[m0], Apan, Ba, acc, raLo, raHi, hi);
      if (mm != 15) geo_loadB(wq_ + (size_t)(m0+2)*65536, boff, Ba);
      geo_compute(m1, SGN[m1], Apan, Bb, acc, raLo, raHi, hi);
      if (mm != 15) geo_loadB(wq_ + (size_t)(m1+2)*65536, boff, Bb);
    }
  }

  // epilogue: normalize each multivector (32 l-rows of one (bs,c) column)
  #pragma unroll
  for (int fn=0; fn<4; ++fn){
    const int c = col0 + wn*64 + fn*16 + lo;
    float s0=0.f, s1=0.f;
    #pragma unroll
    for (int r=0;r<4;r++){
      s0 += acc[0][fn][r]*acc[0][fn][r] + acc[1][fn][r]*acc[1][fn][r];
      s1 += acc[2][fn][r]*acc[2][fn][r] + acc[3][fn][r]*acc[3][fn][r];
    }
    s0 += __shfl_xor(s0,16); s0 += __shfl_xor(s0,32);
    s1 += __shfl_xor(s1,16); s1 += __shfl_xor(s1,32);
    const float r0 = rsqrtf(s0+1e-6f), r1 = rsqrtf(s1+1e-6f);
    #pragma unroll
    for (int fm=0;fm<4;fm++){
      const float rs = (fm<2)? r0 : r1;
      const int bsg = (row0>>5) + wm*2 + (fm>>1);
      const int l0 = (fm&1)*16 + hi*4;
      float v0 = acc[fm][fn][0]*rs, v1 = acc[fm][fn][1]*rs, v2 = acc[fm][fn][2]*rs, v3 = acc[fm][fn][3]*rs;
      if constexpr (EPI==0){
        if (c < 256){ // fold SIG_DIAG into q
          if (sign_neg(l0+0,l0+0)) v0=-v0;
          if (sign_neg(l0+1,l0+1)) v1=-v1;
          if (sign_neg(l0+2,l0+2)) v2=-v2;
          if (sign_neg(l0+3,l0+3)) v3=-v3;
        }
        u16* dst = qkv + ((size_t)bsg*768 + c)*32 + l0;
        *(uint2*)dst = make_uint2(pack2(v0,v1), pack2(v2,v3));
      } else {
        float* dst = dout + ((size_t)bsg*256 + c)*32 + l0;
        *(float4*)dst = make_float4(v0,v1,v2,v3);
      }
    }
  }
}

// ---------------- row norms of Q / K (1024 elems per (bh, s)) ---------------------
__global__ __launch_bounds__(256) void k_norms(const u16* __restrict__ qkv, float* __restrict__ Nq, float* __restrict__ Nk){
  const int t = threadIdx.x, lane = t&63, wid = t>>6;
  const int gr = blockIdx.x*4 + wid;     // 0..16383
  const int sel = gr>>13;                // 0=q, 1=k
  const int idx = gr & 8191;
  const int bh = idx>>9, s = idx&511;
  const int b = bh>>3, h = bh&7;
  const u16* p = qkv + ((size_t)(b*512+s))*24576 + sel*8192 + h*1024 + lane*16;
  uint4 a = *(const uint4*)p;
  uint4 c = *(const uint4*)(p+8);
  float sum = sq2(a.x)+sq2(a.y)+sq2(a.z)+sq2(a.w)+sq2(c.x)+sq2(c.y)+sq2(c.z)+sq2(c.w);
  #pragma unroll
  for (int o=1;o<64;o<<=1) sum += __shfl_xor(sum,o);
  if (lane==0) (sel? Nk : Nq)[bh*512+s] = sum;
}

// ---------------- shared 128x128 MFMA tile engine (linear-row operands) -----------
DEVINL void mm_steps(const u16* Abase, int Astride, const u16* Bbase, int Bstride, int ksteps,
                     u16* Al, u16* Bl, f32x4 (&acc)[4][4], int lane, int wid){
  const int wm = wid>>1, wn = wid&1, lo = lane&15, hi = lane>>4;
  for (int s=0; s<ksteps; ++s){
    const int k0 = s*64;
    #pragma unroll
    for (int c=0;c<4;c++){
      const int gb = (wid*4+c)*64;
      const int idx = gb + lane;
      const int r = idx>>3, j = idx&7;
      const int sw = ((j^(r&7))*8);
      gload_lds16(Abase + (size_t)r*Astride + k0 + sw, Al + gb*8);
      gload_lds16(Bbase + (size_t)r*Bstride + k0 + sw, Bl + gb*8);
    }
    __syncthreads();
    #pragma unroll
    for (int kk=0; kk<2; ++kk){
      bf16x8 af[4], bfr[4];
      #pragma unroll
      for (int f=0;f<4;f++){
        const int ra = wm*64 + f*16 + lo;
        const int jc = kk*4 + hi;
        af[f] = *(const bf16x8*)(Al + ra*64 + ((jc^(ra&7))*8));
        const int rb = wn*64 + f*16 + lo;
        bfr[f] = *(const bf16x8*)(Bl + rb*64 + ((jc^(rb&7))*8));
      }
      #pragma unroll
      for (int fm=0;fm<4;fm++){
        #pragma unroll
        for (int fn=0;fn<4;fn++)
          acc[fm][fn] = __builtin_amdgcn_mfma_f32_16x16x32_bf16(af[fm], bfr[fn], acc[fm][fn], 0,0,0);
      }
    }
    __syncthreads();
  }
}

// ---------------- score: ss + gamma*bivector, write S1 f32 and S1T bf16 -----------
__global__ __launch_bounds__(256) void k_score(const u16* __restrict__ qkv, const float* __restrict__ Nq,
                                               const float* __restrict__ Nk, const float* __restrict__ gptr,
                                               float* __restrict__ S1, u16* __restrict__ S1T){
  __shared__ __align__(16) u16 Al[128*64];
  __shared__ __align__(16) u16 Bl[128*64];
  __shared__ __align__(16) u16 Tl[128*136];
  const int wg = blockIdx.x;
  const int bid = (wg&7)*32 + (wg>>3);
  const int bh = bid>>4, ti=(bid>>2)&3, tj=bid&3;
  const int b = bh>>3, h = bh&7;
  const int i0=ti*128, j0=tj*128;
  const int t=threadIdx.x, lane=t&63, wid=t>>6;
  const int wm=wid>>1, wn=wid&1, lo=lane&15, hi=lane>>4;
  f32x4 acc[4][4];
  #pragma unroll
  for(int a=0;a<4;a++){
    #pragma unroll
    for(int c=0;c<4;c++){ acc[a][c] = (f32x4){0.f,0.f,0.f,0.f}; }
  }
  const u16* Abase = qkv + ((size_t)(b*512+i0))*24576 + h*1024;
  const u16* Bbase = qkv + ((size_t)(b*512+j0))*24576 + 8192 + h*1024;
  mm_steps(Abase, 24576, Bbase, 24576, 16, Al, Bl, acc, lane, wid);
  const float gamma = *gptr;
  const float rhd = 0.17677669529663687f; // 1/sqrt(32)
  float nkv[4];
  #pragma unroll
  for (int fn=0;fn<4;fn++) nkv[fn] = Nk[bh*512 + j0 + wn*64 + fn*16 + lo];
  #pragma unroll
  for (int fm=0;fm<4;fm++){
    #pragma unroll
    for (int r=0;r<4;r++){
      const int iL = wm*64 + fm*16 + hi*4 + r;
      const float nq = Nq[bh*512 + i0 + iL];
      #pragma unroll
      for (int fn=0;fn<4;fn++){
        const int jL = wn*64 + fn*16 + lo;
        const float ss = acc[fm][fn][r];
        const float biv = sqrtf(fmaxf(nq*nkv[fn] - ss*ss, 0.f) + 1e-6f);
        const float sc = (ss + gamma*biv)*rhd;
        S1[((size_t)bh*512 + i0 + iL)*512 + j0 + jL] = sc;
        Tl[jL*136 + iL] = f2bf(sc);
      }
    }
  }
  __syncthreads();
  const int jj = t>>1, half = t&1;
  u16* dst = S1T + ((size_t)bh*512 + (j0+jj))*512 + i0 + half*64;
  #pragma unroll
  for (int q=0;q<8;q++)
    *(uint4*)(dst + q*8) = *(const uint4*)(Tl + jj*136 + half*64 + q*8);
}

// ---------------- row softmax (optionally masked), f32 in -> bf16 probs ----------
__global__ __launch_bounds__(256) void k_softmax(const float* __restrict__ S, const int* __restrict__ mask,
                                                 u16* __restrict__ P, int masked){
  __shared__ float redm[4], reds[4];
  const int row = blockIdx.x;          // bh*512 + i
  const int b = row>>12;
  const float* sp = S + (size_t)row*512;
  const int t = threadIdx.x, lane = t&63, wid = t>>6;
  float v0 = sp[t], v1 = sp[t+256];
  if (masked){
    if (mask[b*512 + t]   == 0) v0 = -1e9f;
    if (mask[b*512 + t+256] == 0) v1 = -1e9f;
  }
  float mx = fmaxf(v0,v1);
  #pragma unroll
  for (int o=1;o<64;o<<=1) mx = fmaxf(mx, __shfl_xor(mx,o));
  if (lane==0) redm[wid]=mx;
  __syncthreads();
  mx = fmaxf(fmaxf(redm[0],redm[1]), fmaxf(redm[2],redm[3]));
  const float e0 = __expf(v0-mx), e1 = __expf(v1-mx);
  float sm = e0+e1;
  #pragma unroll
  for (int o=1;o<64;o<<=1) sm += __shfl_xor(sm,o);
  if (lane==0) reds[wid]=sm;
  __syncthreads();
  sm = reds[0]+reds[1]+reds[2]+reds[3];
  const float inv = 1.f/sm;
  P[(size_t)row*512 + t]     = f2bf(e0*inv);
  P[(size_t)row*512 + t+256] = f2bf(e1*inv);
}

// ---------------- triangle update: S1 += 0.1 * P1 @ S1b (in place, f32) ----------
__global__ __launch_bounds__(256) void k_tri(const u16* __restrict__ P1, const u16* __restrict__ S1T,
                                             float* __restrict__ S1){
  __shared__ __align__(16) u16 Al[128*64];
  __shared__ __align__(16) u16 Bl[128*64];
  const int wg = blockIdx.x;
  const int bid = (wg&7)*32 + (wg>>3);
  const int bh = bid>>4, ti=(bid>>2)&3, tj=bid&3;
  const int i0=ti*128, j0=tj*128;
  const int t=threadIdx.x, lane=t&63, wid=t>>6;
  const int wm=wid>>1, wn=wid&1, lo=lane&15, hi=lane>>4;
  f32x4 acc[4][4];
  #pragma unroll
  for(int a=0;a<4;a++){
    #pragma unroll
    for(int c=0;c<4;c++){ acc[a][c] = (f32x4){0.f,0.f,0.f,0.f}; }
  }
  const u16* Abase = P1  + ((size_t)bh*512 + i0)*512;
  const u16* Bbase = S1T + ((size_t)bh*512 + j0)*512;
  mm_steps(Abase, 512, Bbase, 512, 8, Al, Bl, acc, lane, wid);
  #pragma unroll
  for (int fm=0;fm<4;fm++){
    #pragma unroll
    for (int r=0;r<4;r++){
      const int iL = wm*64 + fm*16 + hi*4 + r;
      #pragma unroll
      for (int fn=0;fn<4;fn++){
        const int jL = wn*64 + fn*16 + lo;
        const size_t idx = ((size_t)bh*512 + i0 + iL)*512 + j0 + jL;
        S1[idx] = S1[idx] + 0.1f*acc[fm][fn][r];
      }
    }
  }
}

// ---------------- transpose V to VT[bh][d][s] ------------------------------------
__global__ __launch_bounds__(256) void k_tr_v(const u16* __restrict__ qkv, u16* __restrict__ VT){
  __shared__ u16 tile[128*129];
  const int bid=blockIdx.x;
  const int bh = bid>>5, dch=(bid>>2)&7, sch=bid&3;
  const int b=bh>>3, h=bh&7;
  const int d0=dch*128, s0=sch*128;
  const int t=threadIdx.x;
  {
    const int r=t>>1, half=t&1;
    const u16* src = qkv + ((size_t)(b*512+s0+r))*24576 + 16384 + h*1024 + d0 + half*64;
    #pragma unroll
    for (int q=0;q<8;q++){
      uint4 v = *(const uint4*)(src + q*8);
      u16* dp = tile + r*129 + half*64 + q*8;
      dp[0]=(u16)(v.x&0xffffu); dp[1]=(u16)(v.x>>16); dp[2]=(u16)(v.y&0xffffu); dp[3]=(u16)(v.y>>16);
      dp[4]=(u16)(v.z&0xffffu); dp[5]=(u16)(v.z>>16); dp[6]=(u16)(v.w&0xffffu); dp[7]=(u16)(v.w>>16);
    }
  }
  __syncthreads();
  {
    const int rr=t>>1, half=t&1;
    u16* dst = VT + ((size_t)bh*1024 + d0+rr)*512 + s0 + half*64;
    #pragma unroll
    for (int q=0;q<4;q++){
      u32 w[8];
      #pragma unroll
      for (int e=0;e<8;e++){
        const int s = half*64 + q*16 + e*2;
        w[e] = (u32)tile[s*129+rr] | ((u32)tile[(s+1)*129+rr]<<16);
      }
      *(uint4*)(dst + q*16)     = make_uint4(w[0],w[1],w[2],w[3]);
      *(uint4*)(dst + q*16 + 8) = make_uint4(w[4],w[5],w[6],w[7]);
    }
  }
}

// ---------------- PV: out = P2 @ V, write transposed xt2[bs*32+l][e] bf16 --------
__global__ __launch_bounds__(256) void k_pv(const u16* __restrict__ P2, const u16* __restrict__ VT,
                                            u16* __restrict__ xt2){
  __shared__ __align__(16) u16 Al[128*64];
  __shared__ __align__(16) u16 Bl[128*64];
  __shared__ __align__(16) u16 Tl[128*136];
  const int wg = blockIdx.x;
  const int bid = (wg&7)*64 + (wg>>3);
  const int bh = bid>>5, ti=(bid>>3)&3, td=bid&7;
  const int b=bh>>3, h=bh&7;
  const int i0=ti*128, d0=td*128;
  const int t=threadIdx.x, lane=t&63, wid=t>>6;
  const int wm=wid>>1, wn=wid&1, lo=lane&15, hi=lane>>4;
  f32x4 acc[4][4];
  #pragma unroll
  for(int a=0;a<4;a++){
    #pragma unroll
    for(int c=0;c<4;c++){ acc[a][c] = (f32x4){0.f,0.f,0.f,0.f}; }
  }
  const u16* Abase = P2 + ((size_t)bh*512 + i0)*512;
  const u16* Bbase = VT + ((size_t)bh*1024 + d0)*512;
  mm_steps(Abase, 512, Bbase, 512, 8, Al, Bl, acc, lane, wid);
  #pragma unroll
  for (int fm=0;fm<4;fm++){
    #pragma unroll
    for (int r=0;r<4;r++){
      const int sL = wm*64 + fm*16 + hi*4 + r;
      #pragma unroll
      for (int fn=0;fn<4;fn++){
        const int dL = wn*64 + fn*16 + lo;
        Tl[sL*136 + dL] = f2bf(acc[fm][fn][r]);
      }
    }
  }
  __syncthreads();
  const int hd0 = td*4;
  #pragma unroll
  for (int u=0;u<16;u++){
    const int seg = t + u*256;
    const int sL = seg>>5, l = seg&31;
    const u16* tp = Tl + sL*136 + l;
    u32 w0 = (u32)tp[0]  | ((u32)tp[32]<<16);
    u32 w1 = (u32)tp[64] | ((u32)tp[96]<<16);
    u16* dst = xt2 + ((size_t)((b*512 + i0 + sL)*32 + l))*256 + h*32 + hd0;
    *(uint2*)dst = make_uint2(w0,w1);
  }
}

extern "C" void kernel_launch(void* const* d_in, const int* in_sizes, int n_in,
                              void* d_out, int out_size, void* d_ws, size_t ws_size,
                              hipStream_t stream) {
  const float* x  = (const float*)d_in[0];
  const float* wq = (const float*)d_in[1];
  const float* wk = (const float*)d_in[2];
  const float* wv = (const float*)d_in[3];
  const float* wo = (const float*)d_in[4];
  const float* gamma = (const float*)d_in[5];
  const int*   mask  = (const int*)d_in[6];
  float* out = (float*)d_out;

  char* ws = (char*)d_ws;
  size_t off = 0;
  auto alloc = [&](size_t n){ char* p = ws + off; off += (n + 255) & ~(size_t)255; return p; };
  u16*  xt  = (u16*) alloc(16777216);   // [32768][256] bf16
  u16*  wT  = (u16*) alloc(16777216);   // [4][32][256][256] bf16
  u16*  qkv = (u16*) alloc(50331648);   // [1024][768][32] bf16
  float* Nq = (float*)alloc(32768);
  float* Nk = (float*)alloc(32768);
  float* S1 = (float*)alloc(16777216);  // [16][512][512] f32
  u16*  S1T = (u16*) alloc(8388608);    // [16][512][512] bf16 (transposed)
  u16*  P2  = (u16*) alloc(8388608);
  u16*  VT  = (u16*) alloc(16777216);   // [16][1024][512] bf16
  u16*  P1  = xt;                       // alias: xt dead after gemm<0>; P1 dead before k_pv writes xt2
  u16*  xt2 = xt;                       // alias: reuse xt region for attention output

  k_tr_x<<<1024, 256, 0, stream>>>(x, xt);
  k_tr_w<<<1024, 256, 0, stream>>>(wq, wk, wv, wo, wT);
  k_geo_gemm<0><<<1536, 256, 0, stream>>>(xt, wT, qkv, nullptr);
  k_norms<<<4096, 256, 0, stream>>>(qkv, Nq, Nk);
  k_score<<<256, 256, 0, stream>>>(qkv, Nq, Nk, gamma, S1, S1T);
  k_softmax<<<8192, 256, 0, stream>>>(S1, mask, P1, 0);
  k_tri<<<256, 256, 0, stream>>>(P1, S1T, S1);
  k_softmax<<<8192, 256, 0, stream>>>(S1, mask, P2, 1);
  k_tr_v<<<512, 256, 0, stream>>>(qkv, VT);
  k_pv<<<512, 256, 0, stream>>>(P2, VT, xt2);
  k_geo_gemm<1><<<512, 256, 0, stream>>>(xt2, wT, nullptr, out);
}

// Round 8
// 622.783 us; speedup vs baseline: 1.7409x; 1.7409x over previous
//
#include <hip/hip_runtime.h>
#include <stdint.h>

typedef unsigned short u16;
typedef unsigned int u32;
typedef __attribute__((ext_vector_type(8))) __bf16 bf16x8;
typedef __attribute__((ext_vector_type(4))) float f32x4;

#define DEVINL __device__ __forceinline__

DEVINL float bf2f(u16 u){ union{u32 i; float f;} c; c.i = ((u32)u)<<16; return c.f; }
DEVINL u16 f2bf(float f){ union{float f; u32 i;} c; c.f=f; u32 u=c.i; return (u16)((u + 0x7fffu + ((u>>16)&1u))>>16); }
DEVINL u32 pack2(float a, float b){ return (u32)f2bf(a) | ((u32)f2bf(b)<<16); }
DEVINL float sq2(u32 u){ float a = bf2f((u16)(u&0xffffu)), b = bf2f((u16)(u>>16)); return a*a + b*b; }

// parity of sign(e_a * e_b) in Cl(4,1): reorder swaps + metric (e4^2 = -1)
DEVINL int sign_neg(int a, int b){
  int s = __popc((a>>1)&b) + __popc((a>>2)&b) + __popc((a>>3)&b) + __popc((a>>4)&b) + ((a&b)>>4);
  return s & 1;
}

constexpr u32 sgn_mask(int m){
  u32 r = 0;
  for (int n=0;n<32;n++){
    int s = __builtin_popcount((m>>1)&n) + __builtin_popcount((m>>2)&n)
          + __builtin_popcount((m>>3)&n) + __builtin_popcount((m>>4)&n) + ((m&n)>>4);
    r |= (u32)(s&1) << n;
  }
  return r;
}
__device__ __constant__ u32 SGNC[32] = {
  sgn_mask(0), sgn_mask(1), sgn_mask(2), sgn_mask(3), sgn_mask(4), sgn_mask(5), sgn_mask(6), sgn_mask(7),
  sgn_mask(8), sgn_mask(9), sgn_mask(10),sgn_mask(11),sgn_mask(12),sgn_mask(13),sgn_mask(14),sgn_mask(15),
  sgn_mask(16),sgn_mask(17),sgn_mask(18),sgn_mask(19),sgn_mask(20),sgn_mask(21),sgn_mask(22),sgn_mask(23),
  sgn_mask(24),sgn_mask(25),sgn_mask(26),sgn_mask(27),sgn_mask(28),sgn_mask(29),sgn_mask(30),sgn_mask(31)};

DEVINL void gload_lds16(const void* g, void* l){
  __builtin_amdgcn_global_load_lds(
    (const __attribute__((address_space(1))) void*)g,
    (__attribute__((address_space(3))) void*)l, 16, 0, 0);
}

// ---------------- transpose x: [bs][i=256][n=32] f32 -> xt [bs*32+n][i] bf16 -----
__global__ __launch_bounds__(256) void k_tr_x(const float* __restrict__ x, u16* __restrict__ xt){
  __shared__ float tile[256][33];
  const int bs = blockIdx.x, t = threadIdx.x;
  const float* xp = x + (size_t)bs*8192 + t*32;
  #pragma unroll
  for (int n=0;n<32;n+=4){
    float4 v = *(const float4*)(xp + n);
    tile[t][n]=v.x; tile[t][n+1]=v.y; tile[t][n+2]=v.z; tile[t][n+3]=v.w;
  }
  __syncthreads();
  const int n = t>>3, i0 = (t&7)*32;
  u16* dst = xt + ((size_t)bs*32 + n)*256 + i0;
  #pragma unroll
  for (int q=0;q<4;q++){
    u32 w0 = pack2(tile[i0+q*8+0][n], tile[i0+q*8+1][n]);
    u32 w1 = pack2(tile[i0+q*8+2][n], tile[i0+q*8+3][n]);
    u32 w2 = pack2(tile[i0+q*8+4][n], tile[i0+q*8+5][n]);
    u32 w3 = pack2(tile[i0+q*8+6][n], tile[i0+q*8+7][n]);
    *(uint4*)(dst + q*8) = make_uint4(w0,w1,w2,w3);
  }
}

// ---------------- transpose w: w[o][i][m] f32 -> wT[wsel][m][o][i] bf16 ----------
__global__ __launch_bounds__(256) void k_tr_w(const float* __restrict__ wq, const float* __restrict__ wk,
                                              const float* __restrict__ wv, const float* __restrict__ wo,
                                              u16* __restrict__ wT){
  __shared__ float tile[256][33];
  const int bid = blockIdx.x, t = threadIdx.x;
  const int wsel = bid>>8, o = bid&255;
  const float* w = wsel==0?wq: wsel==1?wk: wsel==2?wv: wo;
  const float* wp = w + ((size_t)o*256 + t)*32;
  #pragma unroll
  for (int m=0;m<32;m+=4){
    float4 v = *(const float4*)(wp + m);
    tile[t][m]=v.x; tile[t][m+1]=v.y; tile[t][m+2]=v.z; tile[t][m+3]=v.w;
  }
  __syncthreads();
  const int m = t>>3, i0 = (t&7)*32;
  u16* dst = wT + (((size_t)wsel*32 + m)*256 + o)*256 + i0;
  #pragma unroll
  for (int q=0;q<4;q++){
    u32 w0 = pack2(tile[i0+q*8+0][m], tile[i0+q*8+1][m]);
    u32 w1 = pack2(tile[i0+q*8+2][m], tile[i0+q*8+3][m]);
    u32 w2 = pack2(tile[i0+q*8+4][m], tile[i0+q*8+5][m]);
    u32 w3 = pack2(tile[i0+q*8+6][m], tile[i0+q*8+7][m]);
    *(uint4*)(dst + q*8) = make_uint4(w0,w1,w2,w3);
  }
}

// ---- geo GEMM helpers -----------------------------------------------------------
DEVINL void geo_stageA(const u16* __restrict__ xt, int row0, int q, u16* Apan, int wid, int lane){
  #pragma unroll
  for (int c=0;c<4;c++){
    const int base = (wid*4+c)*64;
    const int idx = base + lane;
    const int rr = idx>>3, g = idx&7;
    gload_lds16(xt + (size_t)(row0+rr)*256 + q*64 + ((g^(rr&7))*8), Apan + base*8);
  }
}
DEVINL void geo_stageB(const u16* __restrict__ wp, int o0, int flat, u16* dst, int wid, int lane){
  const int m = flat&31, qq = flat>>5;
  const u16* bsrc = wp + (size_t)m*65536 + qq*64;
  #pragma unroll
  for (int c=0;c<4;c++){
    const int base = (wid*4+c)*64;
    const int idx = base + lane;
    const int r = idx>>3, j = idx&7;
    gload_lds16(bsrc + (size_t)(o0+r)*256 + ((j^(r&7))*8), dst + base*8);
  }
}
DEVINL void geo_compute(int m, u32 smask, const u16* __restrict__ Ab, const u16* __restrict__ Bb,
                        f32x4 (&acc)[4][4], int wm, int wn, int lo, int hi){
  #pragma unroll
  for (int kk=0; kk<2; ++kk){
    bf16x8 af[4], bfr[4];
    #pragma unroll
    for (int f=0;f<4;f++){
      const int ra = wm*64 + f*16 + lo;
      const int rowx = (ra&31)^m;
      const int rr = (ra&96)|rowx;
      const u32 sx = ((smask >> rowx) & 1u) ? 0x80008000u : 0u;
      const int gA = kk*4 + hi;
      uint4 av = *(const uint4*)(Ab + rr*64 + ((gA ^ (rr&7))*8));
      av.x^=sx; av.y^=sx; av.z^=sx; av.w^=sx;
      af[f] = *(const bf16x8*)&av;
      const int rb = wn*64 + f*16 + lo;
      bfr[f] = *(const bf16x8*)(Bb + rb*64 + ((gA^(rb&7))*8));
    }
    __builtin_amdgcn_s_setprio(1);
    #pragma unroll
    for (int fm=0;fm<4;fm++){
      #pragma unroll
      for (int fn=0;fn<4;fn++)
        acc[fm][fn] = __builtin_amdgcn_mfma_f32_16x16x32_bf16(af[fm], bfr[fn], acc[fm][fn], 0,0,0);
    }
    __builtin_amdgcn_s_setprio(0);
  }
}

// geo GEMM: out[bs,o,l] = sum_{m,i} xt[bs,l^m,i]*sign(m,l^m)*wT[m][o][i]
// 128x128 tile, 4 waves. A i-quarter LDS-resident (16 KB); B triple-buffered
// (48 KB), staged 2 phases ahead; ONE raw s_barrier + counted vmcnt(4) per phase.
// EPI=0 also fuses the Q/K row-norms into the epilogue.
template<int EPI>
__global__ __launch_bounds__(256) void k_geo_gemm(const u16* __restrict__ xt, const u16* __restrict__ wT,
                                                  u16* __restrict__ qkv, float* __restrict__ dout,
                                                  float* __restrict__ Nq, float* __restrict__ Nk){
  constexpr int NT = (EPI==0)?6:2;
  constexpr int NWG = 256*NT;
  __shared__ __align__(16) u16 Apan[128*64];     // 16 KB
  __shared__ __align__(16) u16 Bp[3*128*64];     // 48 KB triple buffer
  const int wg = blockIdx.x;
  const int bid = (wg&7)*(NWG/8) + (wg>>3);      // bijective XCD chunking, tn-major
  const int tn = bid >> 8;
  const int tm = bid & 255;
  const int row0 = tm*128, col0 = tn*128;
  const int wsel = (EPI==0)? (col0>>8) : 3;
  const int o0   = (EPI==0)? (col0&255) : col0;
  const u16* wp = wT + (size_t)wsel*32*256*256;
  const int t = threadIdx.x, lane = t&63, wid = t>>6;
  const int wm = wid>>1, wn = wid&1, lo = lane&15, hi = lane>>4;

  f32x4 acc[4][4];
  #pragma unroll
  for(int a=0;a<4;a++){
    #pragma unroll
    for(int b=0;b<4;b++){ acc[a][b] = (f32x4){0.f,0.f,0.f,0.f}; }
  }

  // prologue: A(0) + B(0),B(1); keep B(1) in flight
  geo_stageA(xt, row0, 0, Apan, wid, lane);
  geo_stageB(wp, o0, 0, Bp,        wid, lane);
  geo_stageB(wp, o0, 1, Bp + 8192, wid, lane);
  asm volatile("s_waitcnt vmcnt(4)" ::: "memory");
  __builtin_amdgcn_s_barrier();

  int cs = 0;
  for (int q=0; q<4; ++q){
    for (int m=0; m<32; ++m){
      const int flat = q*32 + m;
      const int ss = (cs==0)? 2 : cs-1;            // slot (flat+2)%3
      if (m==0 && q>0){
        // quarter boundary: restage A (all waves passed last barrier -> Apan free)
        geo_stageA(xt, row0, q, Apan, wid, lane);
        if (flat+2 < 128) geo_stageB(wp, o0, flat+2, Bp + ss*8192, wid, lane);
        asm volatile("s_waitcnt vmcnt(4)" ::: "memory");   // A landed; newest B stays in flight
        __builtin_amdgcn_s_barrier();
      } else {
        if (flat+2 < 128) geo_stageB(wp, o0, flat+2, Bp + ss*8192, wid, lane);
      }
      geo_compute(m, SGNC[m], Apan, Bp + cs*8192, acc, wm, wn, lo, hi);
      if (flat+2 < 128) asm volatile("s_waitcnt vmcnt(4)" ::: "memory");
      else              asm volatile("s_waitcnt vmcnt(0)" ::: "memory");
      __builtin_amdgcn_s_barrier();
      cs = (cs==2)? 0 : cs+1;
    }
  }

  // epilogue: normalize each multivector; EPI==0 also emits fused Nq/Nk
  float hacc[2][2] = {{0.f,0.f},{0.f,0.f}};
  #pragma unroll
  for (int fn=0; fn<4; ++fn){
    const int c = col0 + wn*64 + fn*16 + lo;
    float s0=0.f, s1=0.f;
    #pragma unroll
    for (int r=0;r<4;r++){
      s0 += acc[0][fn][r]*acc[0][fn][r] + acc[1][fn][r]*acc[1][fn][r];
      s1 += acc[2][fn][r]*acc[2][fn][r] + acc[3][fn][r]*acc[3][fn][r];
    }
    s0 += __shfl_xor(s0,16); s0 += __shfl_xor(s0,32);
    s1 += __shfl_xor(s1,16); s1 += __shfl_xor(s1,32);
    if constexpr (EPI==0){
      hacc[fn>>1][0] += s0/(s0+1e-6f);
      hacc[fn>>1][1] += s1/(s1+1e-6f);
    }
    const float r0 = rsqrtf(s0+1e-6f), r1 = rsqrtf(s1+1e-6f);
    #pragma unroll
    for (int fm=0;fm<4;fm++){
      const float rs = (fm<2)? r0 : r1;
      const int bsg = (row0>>5) + wm*2 + (fm>>1);
      const int l0 = (fm&1)*16 + hi*4;
      float v0 = acc[fm][fn][0]*rs, v1 = acc[fm][fn][1]*rs, v2 = acc[fm][fn][2]*rs, v3 = acc[fm][fn][3]*rs;
      if constexpr (EPI==0){
        if (c < 256){ // fold SIG_DIAG into q
          if (sign_neg(l0+0,l0+0)) v0=-v0;
          if (sign_neg(l0+1,l0+1)) v1=-v1;
          if (sign_neg(l0+2,l0+2)) v2=-v2;
          if (sign_neg(l0+3,l0+3)) v3=-v3;
        }
        u16* dst = qkv + ((size_t)bsg*768 + c)*32 + l0;
        *(uint2*)dst = make_uint2(pack2(v0,v1), pack2(v2,v3));
      } else {
        float* dst = dout + ((size_t)bsg*256 + c)*32 + l0;
        *(float4*)dst = make_float4(v0,v1,v2,v3);
      }
    }
  }
  if constexpr (EPI==0){
    if (tn < 4){
      #pragma unroll
      for (int hs=0; hs<2; ++hs){
        #pragma unroll
        for (int p=0; p<2; ++p){
          float v = hacc[hs][p];
          v += __shfl_xor(v,1); v += __shfl_xor(v,2);
          v += __shfl_xor(v,4); v += __shfl_xor(v,8);
          hacc[hs][p] = v;
        }
      }
      if (lo==0 && hi==0){
        const int hb = ((col0&255)>>5) + wn*2;
        float* nd = (tn<2)? Nq : Nk;
        #pragma unroll
        for (int hs=0; hs<2; ++hs){
          #pragma unroll
          for (int p=0; p<2; ++p){
            const int bsf = (row0>>5) + wm*2 + p;
            const int b = bsf>>9, s = bsf&511;
            nd[((size_t)(b*8 + hb+hs))*512 + s] = hacc[hs][p];
          }
        }
      }
    }
  }
}

// ---------------- shared 128x128 MFMA tile engine (linear-row operands) -----------
DEVINL void mm_steps(const u16* Abase, int Astride, const u16* Bbase, int Bstride, int ksteps,
                     u16* Al, u16* Bl, f32x4 (&acc)[4][4], int lane, int wid){
  const int wm = wid>>1, wn = wid&1, lo = lane&15, hi = lane>>4;
  for (int s=0; s<ksteps; ++s){
    const int k0 = s*64;
    #pragma unroll
    for (int c=0;c<4;c++){
      const int gb = (wid*4+c)*64;
      const int idx = gb + lane;
      const int r = idx>>3, j = idx&7;
      const int sw = ((j^(r&7))*8);
      gload_lds16(Abase + (size_t)r*Astride + k0 + sw, Al + gb*8);
      gload_lds16(Bbase + (size_t)r*Bstride + k0 + sw, Bl + gb*8);
    }
    __syncthreads();
    #pragma unroll
    for (int kk=0; kk<2; ++kk){
      bf16x8 af[4], bfr[4];
      #pragma unroll
      for (int f=0;f<4;f++){
        const int ra = wm*64 + f*16 + lo;
        const int jc = kk*4 + hi;
        af[f] = *(const bf16x8*)(Al + ra*64 + ((jc^(ra&7))*8));
        const int rb = wn*64 + f*16 + lo;
        bfr[f] = *(const bf16x8*)(Bl + rb*64 + ((jc^(rb&7))*8));
      }
      #pragma unroll
      for (int fm=0;fm<4;fm++){
        #pragma unroll
        for (int fn=0;fn<4;fn++)
          acc[fm][fn] = __builtin_amdgcn_mfma_f32_16x16x32_bf16(af[fm], bfr[fn], acc[fm][fn], 0,0,0);
      }
    }
    __syncthreads();
  }
}

// ---------------- score: ss + gamma*bivector, write S1 f32 and S1T bf16 -----------
__global__ __launch_bounds__(256) void k_score(const u16* __restrict__ qkv, const float* __restrict__ Nq,
                                               const float* __restrict__ Nk, const float* __restrict__ gptr,
                                               float* __restrict__ S1, u16* __restrict__ S1T){
  __shared__ __align__(16) u16 Al[128*64];
  __shared__ __align__(16) u16 Bl[128*64];
  __shared__ __align__(16) u16 Tl[128*136];
  const int wg = blockIdx.x;
  const int bid = (wg&7)*32 + (wg>>3);
  const int bh = bid>>4, ti=(bid>>2)&3, tj=bid&3;
  const int b = bh>>3, h = bh&7;
  const int i0=ti*128, j0=tj*128;
  const int t=threadIdx.x, lane=t&63, wid=t>>6;
  const int wm=wid>>1, wn=wid&1, lo=lane&15, hi=lane>>4;
  f32x4 acc[4][4];
  #pragma unroll
  for(int a=0;a<4;a++){
    #pragma unroll
    for(int c=0;c<4;c++){ acc[a][c] = (f32x4){0.f,0.f,0.f,0.f}; }
  }
  const u16* Abase = qkv + ((size_t)(b*512+i0))*24576 + h*1024;
  const u16* Bbase = qkv + ((size_t)(b*512+j0))*24576 + 8192 + h*1024;
  mm_steps(Abase, 24576, Bbase, 24576, 16, Al, Bl, acc, lane, wid);
  const float gamma = *gptr;
  const float rhd = 0.17677669529663687f; // 1/sqrt(32)
  float nkv[4];
  #pragma unroll
  for (int fn=0;fn<4;fn++) nkv[fn] = Nk[bh*512 + j0 + wn*64 + fn*16 + lo];
  #pragma unroll
  for (int fm=0;fm<4;fm++){
    #pragma unroll
    for (int r=0;r<4;r++){
      const int iL = wm*64 + fm*16 + hi*4 + r;
      const float nq = Nq[bh*512 + i0 + iL];
      #pragma unroll
      for (int fn=0;fn<4;fn++){
        const int jL = wn*64 + fn*16 + lo;
        const float ss = acc[fm][fn][r];
        const float biv = sqrtf(fmaxf(nq*nkv[fn] - ss*ss, 0.f) + 1e-6f);
        const float sc = (ss + gamma*biv)*rhd;
        S1[((size_t)bh*512 + i0 + iL)*512 + j0 + jL] = sc;
        Tl[jL*136 + iL] = f2bf(sc);
      }
    }
  }
  __syncthreads();
  const int jj = t>>1, half = t&1;
  u16* dst = S1T + ((size_t)bh*512 + (j0+jj))*512 + i0 + half*64;
  #pragma unroll
  for (int q=0;q<8;q++)
    *(uint4*)(dst + q*8) = *(const uint4*)(Tl + jj*136 + half*64 + q*8);
}

// ---------------- row softmax (optionally masked), f32 in -> bf16 probs ----------
__global__ __launch_bounds__(256) void k_softmax(const float* __restrict__ S, const int* __restrict__ mask,
                                                 u16* __restrict__ P, int masked){
  __shared__ float redm[4], reds[4];
  const int row = blockIdx.x;          // bh*512 + i
  const int b = row>>12;
  const float* sp = S + (size_t)row*512;
  const int t = threadIdx.x, lane = t&63, wid = t>>6;
  float v0 = sp[t], v1 = sp[t+256];
  if (masked){
    if (mask[b*512 + t]   == 0) v0 = -1e9f;
    if (mask[b*512 + t+256] == 0) v1 = -1e9f;
  }
  float mx = fmaxf(v0,v1);
  #pragma unroll
  for (int o=1;o<64;o<<=1) mx = fmaxf(mx, __shfl_xor(mx,o));
  if (lane==0) redm[wid]=mx;
  __syncthreads();
  mx = fmaxf(fmaxf(redm[0],redm[1]), fmaxf(redm[2],redm[3]));
  const float e0 = __expf(v0-mx), e1 = __expf(v1-mx);
  float sm = e0+e1;
  #pragma unroll
  for (int o=1;o<64;o<<=1) sm += __shfl_xor(sm,o);
  if (lane==0) reds[wid]=sm;
  __syncthreads();
  sm = reds[0]+reds[1]+reds[2]+reds[3];
  const float inv = 1.f/sm;
  P[(size_t)row*512 + t]     = f2bf(e0*inv);
  P[(size_t)row*512 + t+256] = f2bf(e1*inv);
}

// ---------------- triangle update: S1 += 0.1 * P1 @ S1b (in place, f32) ----------
__global__ __launch_bounds__(256) void k_tri(const u16* __restrict__ P1, const u16* __restrict__ S1T,
                                             float* __restrict__ S1){
  __shared__ __align__(16) u16 Al[128*64];
  __shared__ __align__(16) u16 Bl[128*64];
  const int wg = blockIdx.x;
  const int bid = (wg&7)*32 + (wg>>3);
  const int bh = bid>>4, ti=(bid>>2)&3, tj=bid&3;
  const int i0=ti*128, j0=tj*128;
  const int t=threadIdx.x, lane=t&63, wid=t>>6;
  const int wm=wid>>1, wn=wid&1, lo=lane&15, hi=lane>>4;
  f32x4 acc[4][4];
  #pragma unroll
  for(int a=0;a<4;a++){
    #pragma unroll
    for(int c=0;c<4;c++){ acc[a][c] = (f32x4){0.f,0.f,0.f,0.f}; }
  }
  const u16* Abase = P1  + ((size_t)bh*512 + i0)*512;
  const u16* Bbase = S1T + ((size_t)bh*512 + j0)*512;
  mm_steps(Abase, 512, Bbase, 512, 8, Al, Bl, acc, lane, wid);
  #pragma unroll
  for (int fm=0;fm<4;fm++){
    #pragma unroll
    for (int r=0;r<4;r++){
      const int iL = wm*64 + fm*16 + hi*4 + r;
      #pragma unroll
      for (int fn=0;fn<4;fn++){
        const int jL = wn*64 + fn*16 + lo;
        const size_t idx = ((size_t)bh*512 + i0 + iL)*512 + j0 + jL;
        S1[idx] = S1[idx] + 0.1f*acc[fm][fn][r];
      }
    }
  }
}

// ---------------- transpose V to VT[bh][d][s] ------------------------------------
__global__ __launch_bounds__(256) void k_tr_v(const u16* __restrict__ qkv, u16* __restrict__ VT){
  __shared__ u16 tile[128*129];
  const int bid=blockIdx.x;
  const int bh = bid>>5, dch=(bid>>2)&7, sch=bid&3;
  const int b=bh>>3, h=bh&7;
  const int d0=dch*128, s0=sch*128;
  const int t=threadIdx.x;
  {
    const int r=t>>1, half=t&1;
    const u16* src = qkv + ((size_t)(b*512+s0+r))*24576 + 16384 + h*1024 + d0 + half*64;
    #pragma unroll
    for (int q=0;q<8;q++){
      uint4 v = *(const uint4*)(src + q*8);
      u16* dp = tile + r*129 + half*64 + q*8;
      dp[0]=(u16)(v.x&0xffffu); dp[1]=(u16)(v.x>>16); dp[2]=(u16)(v.y&0xffffu); dp[3]=(u16)(v.y>>16);
      dp[4]=(u16)(v.z&0xffffu); dp[5]=(u16)(v.z>>16); dp[6]=(u16)(v.w&0xffffu); dp[7]=(u16)(v.w>>16);
    }
  }
  __syncthreads();
  {
    const int rr=t>>1, half=t&1;
    u16* dst = VT + ((size_t)bh*1024 + d0+rr)*512 + s0 + half*64;
    #pragma unroll
    for (int q=0;q<4;q++){
      u32 w[8];
      #pragma unroll
      for (int e=0;e<8;e++){
        const int s = half*64 + q*16 + e*2;
        w[e] = (u32)tile[s*129+rr] | ((u32)tile[(s+1)*129+rr]<<16);
      }
      *(uint4*)(dst + q*16)     = make_uint4(w[0],w[1],w[2],w[3]);
      *(uint4*)(dst + q*16 + 8) = make_uint4(w[4],w[5],w[6],w[7]);
    }
  }
}

// ---------------- PV: out = P2 @ V, write transposed xt2[bs*32+l][e] bf16 --------
__global__ __launch_bounds__(256) void k_pv(const u16* __restrict__ P2, const u16* __restrict__ VT,
                                            u16* __restrict__ xt2){
  __shared__ __align__(16) u16 Al[128*64];
  __shared__ __align__(16) u16 Bl[128*64];
  __shared__ __align__(16) u16 Tl[128*136];
  const int wg = blockIdx.x;
  const int bid = (wg&7)*64 + (wg>>3);
  const int bh = bid>>5, ti=(bid>>3)&3, td=bid&7;
  const int b=bh>>3, h=bh&7;
  const int i0=ti*128, d0=td*128;
  const int t=threadIdx.x, lane=t&63, wid=t>>6;
  const int wm=wid>>1, wn=wid&1, lo=lane&15, hi=lane>>4;
  f32x4 acc[4][4];
  #pragma unroll
  for(int a=0;a<4;a++){
    #pragma unroll
    for(int c=0;c<4;c++){ acc[a][c] = (f32x4){0.f,0.f,0.f,0.f}; }
  }
  const u16* Abase = P2 + ((size_t)bh*512 + i0)*512;
  const u16* Bbase = VT + ((size_t)bh*1024 + d0)*512;
  mm_steps(Abase, 512, Bbase, 512, 8, Al, Bl, acc, lane, wid);
  #pragma unroll
  for (int fm=0;fm<4;fm++){
    #pragma unroll
    for (int r=0;r<4;r++){
      const int sL = wm*64 + fm*16 + hi*4 + r;
      #pragma unroll
      for (int fn=0;fn<4;fn++){
        const int dL = wn*64 + fn*16 + lo;
        Tl[sL*136 + dL] = f2bf(acc[fm][fn][r]);
      }
    }
  }
  __syncthreads();
  const int hd0 = td*4;
  #pragma unroll
  for (int u=0;u<16;u++){
    const int seg = t + u*256;
    const int sL = seg>>5, l = seg&31;
    const u16* tp = Tl + sL*136 + l;
    u32 w0 = (u32)tp[0]  | ((u32)tp[32]<<16);
    u32 w1 = (u32)tp[64] | ((u32)tp[96]<<16);
    u16* dst = xt2 + ((size_t)((b*512 + i0 + sL)*32 + l))*256 + h*32 + hd0;
    *(uint2*)dst = make_uint2(w0,w1);
  }
}

extern "C" void kernel_launch(void* const* d_in, const int* in_sizes, int n_in,
                              void* d_out, int out_size, void* d_ws, size_t ws_size,
                              hipStream_t stream) {
  const float* x  = (const float*)d_in[0];
  const float* wq = (const float*)d_in[1];
  const float* wk = (const float*)d_in[2];
  const float* wv = (const float*)d_in[3];
  const float* wo = (const float*)d_in[4];
  const float* gamma = (const float*)d_in[5];
  const int*   mask  = (const int*)d_in[6];
  float* out = (float*)d_out;

  char* ws = (char*)d_ws;
  size_t off = 0;
  auto alloc = [&](size_t n){ char* p = ws + off; off += (n + 255) & ~(size_t)255; return p; };
  u16*  xt  = (u16*) alloc(16777216);   // [32768][256] bf16
  u16*  wT  = (u16*) alloc(16777216);   // [4][32][256][256] bf16
  u16*  qkv = (u16*) alloc(50331648);   // [1024][768][32] bf16
  float* Nq = (float*)alloc(32768);
  float* Nk = (float*)alloc(32768);
  float* S1 = (float*)alloc(16777216);  // [16][512][512] f32
  u16*  S1T = (u16*) alloc(8388608);    // [16][512][512] bf16 (transposed)
  u16*  P2  = (u16*) alloc(8388608);
  u16*  VT  = (u16*) alloc(16777216);   // [16][1024][512] bf16
  u16*  P1  = xt;                       // alias: xt dead after gemm<0>; P1 dead before k_pv writes xt2
  u16*  xt2 = xt;                       // alias: reuse xt region for attention output

  k_tr_x<<<1024, 256, 0, stream>>>(x, xt);
  k_tr_w<<<1024, 256, 0, stream>>>(wq, wk, wv, wo, wT);
  k_geo_gemm<0><<<1536, 256, 0, stream>>>(xt, wT, qkv, nullptr, Nq, Nk);
  k_score<<<256, 256, 0, stream>>>(qkv, Nq, Nk, gamma, S1, S1T);
  k_softmax<<<8192, 256, 0, stream>>>(S1, mask, P1, 0);
  k_tri<<<256, 256, 0, stream>>>(P1, S1T, S1);
  k_softmax<<<8192, 256, 0, stream>>>(S1, mask, P2, 1);
  k_tr_v<<<512, 256, 0, stream>>>(qkv, VT);
  k_pv<<<512, 256, 0, stream>>>(P2, VT, xt2);
  k_geo_gemm<1><<<512, 256, 0, stream>>>(xt2, wT, nullptr, out, nullptr, nullptr);
}

// Round 9
// 545.928 us; speedup vs baseline: 1.9860x; 1.1408x over previous
//
#include <hip/hip_runtime.h>
#include <stdint.h>

typedef unsigned short u16;
typedef unsigned int u32;
typedef __attribute__((ext_vector_type(8))) __bf16 bf16x8;
typedef __attribute__((ext_vector_type(4))) float f32x4;

#define DEVINL __device__ __forceinline__

DEVINL float bf2f(u16 u){ union{u32 i; float f;} c; c.i = ((u32)u)<<16; return c.f; }
DEVINL u16 f2bf(float f){ union{float f; u32 i;} c; c.f=f; u32 u=c.i; return (u16)((u + 0x7fffu + ((u>>16)&1u))>>16); }
DEVINL u32 pack2(float a, float b){ return (u32)f2bf(a) | ((u32)f2bf(b)<<16); }
DEVINL float sq2(u32 u){ float a = bf2f((u16)(u&0xffffu)), b = bf2f((u16)(u>>16)); return a*a + b*b; }

// parity of sign(e_a * e_b) in Cl(4,1): reorder swaps + metric (e4^2 = -1)
DEVINL int sign_neg(int a, int b){
  int s = __popc((a>>1)&b) + __popc((a>>2)&b) + __popc((a>>3)&b) + __popc((a>>4)&b) + ((a&b)>>4);
  return s & 1;
}

constexpr u32 sgn_mask(int m){
  u32 r = 0;
  for (int n=0;n<32;n++){
    int s = __builtin_popcount((m>>1)&n) + __builtin_popcount((m>>2)&n)
          + __builtin_popcount((m>>3)&n) + __builtin_popcount((m>>4)&n) + ((m&n)>>4);
    r |= (u32)(s&1) << n;
  }
  return r;
}
__device__ __constant__ u32 SGNC[32] = {
  sgn_mask(0), sgn_mask(1), sgn_mask(2), sgn_mask(3), sgn_mask(4), sgn_mask(5), sgn_mask(6), sgn_mask(7),
  sgn_mask(8), sgn_mask(9), sgn_mask(10),sgn_mask(11),sgn_mask(12),sgn_mask(13),sgn_mask(14),sgn_mask(15),
  sgn_mask(16),sgn_mask(17),sgn_mask(18),sgn_mask(19),sgn_mask(20),sgn_mask(21),sgn_mask(22),sgn_mask(23),
  sgn_mask(24),sgn_mask(25),sgn_mask(26),sgn_mask(27),sgn_mask(28),sgn_mask(29),sgn_mask(30),sgn_mask(31)};

DEVINL void gload_lds16(const void* g, void* l){
  __builtin_amdgcn_global_load_lds(
    (const __attribute__((address_space(1))) void*)g,
    (__attribute__((address_space(3))) void*)l, 16, 0, 0);
}

// ---------------- transpose x: [bs][i=256][n=32] f32 -> xt [bs*32+n][i] bf16 -----
__global__ __launch_bounds__(256) void k_tr_x(const float* __restrict__ x, u16* __restrict__ xt){
  __shared__ float tile[256][33];
  const int bs = blockIdx.x, t = threadIdx.x;
  const float* xp = x + (size_t)bs*8192 + t*32;
  #pragma unroll
  for (int n=0;n<32;n+=4){
    float4 v = *(const float4*)(xp + n);
    tile[t][n]=v.x; tile[t][n+1]=v.y; tile[t][n+2]=v.z; tile[t][n+3]=v.w;
  }
  __syncthreads();
  const int n = t>>3, i0 = (t&7)*32;
  u16* dst = xt + ((size_t)bs*32 + n)*256 + i0;
  #pragma unroll
  for (int q=0;q<4;q++){
    u32 w0 = pack2(tile[i0+q*8+0][n], tile[i0+q*8+1][n]);
    u32 w1 = pack2(tile[i0+q*8+2][n], tile[i0+q*8+3][n]);
    u32 w2 = pack2(tile[i0+q*8+4][n], tile[i0+q*8+5][n]);
    u32 w3 = pack2(tile[i0+q*8+6][n], tile[i0+q*8+7][n]);
    *(uint4*)(dst + q*8) = make_uint4(w0,w1,w2,w3);
  }
}

// ---------------- transpose w into MFMA-fragment order -----------------------------
// wT3[wsel][m][q][o_blk][kk][lane][e]: lane = (o&15) + k8*16, i = q*64+kk*32+k8*8+e
__global__ __launch_bounds__(256) void k_tr_w(const float* __restrict__ wq, const float* __restrict__ wk,
                                              const float* __restrict__ wv, const float* __restrict__ wo,
                                              u16* __restrict__ wT3){
  __shared__ float tile[256][33];
  const int bid = blockIdx.x, t = threadIdx.x;
  const int wsel = bid>>8, o = bid&255;
  const float* w = wsel==0?wq: wsel==1?wk: wsel==2?wv: wo;
  const float* wp = w + ((size_t)o*256 + t)*32;
  #pragma unroll
  for (int m=0;m<32;m+=4){
    float4 v = *(const float4*)(wp + m);
    tile[t][m]=v.x; tile[t][m+1]=v.y; tile[t][m+2]=v.z; tile[t][m+3]=v.w;
  }
  __syncthreads();
  const int m = t>>3, sub = t&7;
  const int q = sub>>1, kk = sub&1;
  const int c = o&15, obk = o>>4;
  const size_t base = (((((size_t)wsel*32 + m)*4 + q)*16 + obk)*2 + kk)*512;
  #pragma unroll
  for (int k8=0;k8<4;k8++){
    const int i0 = sub*32 + k8*8;
    u32 w0 = pack2(tile[i0+0][m], tile[i0+1][m]);
    u32 w1 = pack2(tile[i0+2][m], tile[i0+3][m]);
    u32 w2 = pack2(tile[i0+4][m], tile[i0+5][m]);
    u32 w3 = pack2(tile[i0+6][m], tile[i0+7][m]);
    *(uint4*)(wT3 + base + (size_t)(c + k8*16)*8) = make_uint4(w0,w1,w2,w3);
  }
}

// geo GEMM: out[bs,o,l] = sum_{m,i} xt[bs,l^m,i]*sign(m,l^m)*wT[m][o][i]
// 128x128 tile, 4 waves (2x2). A i-quarter LDS-resident (16 KB); per-m blade
// perm+sign at fragment read via XOR-delta addressing + per-lane sign words.
// B streamed global->registers from fragment-ordered wT3 (coalesced 1KB loads,
// L2-resident per XCD). NO barriers / NO LDS traffic for B in the m-loop.
template<int EPI>
__global__ __launch_bounds__(256) void k_geo_gemm(const u16* __restrict__ xt, const u16* __restrict__ wT3,
                                                  u16* __restrict__ qkv, float* __restrict__ dout,
                                                  float* __restrict__ Nq, float* __restrict__ Nk){
  constexpr int NT = (EPI==0)?6:2;
  constexpr int NWG = 256*NT;
  __shared__ __align__(16) u16 Apan[128*64];     // 16 KB
  const int wg = blockIdx.x;
  const int bid = (wg&7)*(NWG/8) + (wg>>3);      // bijective XCD chunking, tn-major
  const int tn = bid >> 8;
  const int tm = bid & 255;
  const int row0 = tm*128, col0 = tn*128;
  const int wsel = (EPI==0)? (col0>>8) : 3;
  const int o0   = (EPI==0)? (col0&255) : col0;
  const u16* Wp = wT3 + (size_t)wsel*2097152;    // panel base (u16)
  const int t = threadIdx.x, lane = t&63, wid = t>>6;
  const int wm = wid>>1, wn = wid&1, lo = lane&15, hi = lane>>4;

  // A base byte-offsets (m=0) and per-lane sign words
  int baseA[4][2]; u32 sgnw[4];
  #pragma unroll
  for (int f=0; f<4; ++f){
    const int ra = wm*64 + f*16 + lo;
    #pragma unroll
    for (int kk=0; kk<2; ++kk)
      baseA[f][kk] = ra*128 + (((kk*4+hi) ^ (lo&7))*16);
    const int rl = ra & 31;
    u32 sw = 0;
    for (int m=0;m<32;m++) sw |= ((SGNC[m] >> ((rl^m)&31)) & 1u) << m;
    sgnw[f] = sw;
  }
  // B fragment offsets (u16 units) within a (m,q) super-block
  int boff[4][2];
  #pragma unroll
  for (int fn=0; fn<4; ++fn){
    const int ob = (o0>>4) + wn*4 + fn;
    #pragma unroll
    for (int kk=0; kk<2; ++kk)
      boff[fn][kk] = (ob*2+kk)*512 + lane*8;
  }

  f32x4 acc[4][4];
  #pragma unroll
  for(int a=0;a<4;a++){
    #pragma unroll
    for(int b=0;b<4;b++){ acc[a][b] = (f32x4){0.f,0.f,0.f,0.f}; }
  }
  const char* Ab = (const char*)Apan;

  for (int q=0; q<4; ++q){
    __syncthreads();                 // previous quarter fully consumed
    #pragma unroll
    for (int c=0;c<4;c++){
      const int base = (wid*4+c)*64;
      const int idx = base + lane;
      const int rr = idx>>3, g = idx&7;
      gload_lds16(xt + (size_t)(row0+rr)*256 + q*64 + ((g^(rr&7))*8), Apan + base*8);
    }
    __syncthreads();                 // drain: A quarter visible
    const u16* Wq = Wp + (size_t)q*16384;
    for (int m=0; m<32; ++m){
      const u16* Wm = Wq + (size_t)m*65536;
      // issue B fragment loads (coalesced dwordx4; covered by A-side work below)
      uint4 Br[8];
      #pragma unroll
      for (int fn=0; fn<4; ++fn){
        #pragma unroll
        for (int kk=0; kk<2; ++kk)
          Br[fn*2+kk] = *(const uint4*)(Wm + boff[fn][kk]);
      }
      // A fragments: XOR-delta addressing + sign-word masks
      const int dlt = (m<<7) | ((m&7)<<4);
      bf16x8 af[4][2];
      #pragma unroll
      for (int f=0; f<4; ++f){
        const u32 b = (sgnw[f] >> m) & 1u;
        const u32 msk = (0u - b) & 0x80008000u;
        #pragma unroll
        for (int kk=0; kk<2; ++kk){
          uint4 av = *(const uint4*)(Ab + (baseA[f][kk] ^ dlt));
          av.x^=msk; av.y^=msk; av.z^=msk; av.w^=msk;
          af[f][kk] = *(const bf16x8*)&av;
        }
      }
      __builtin_amdgcn_s_setprio(1);
      #pragma unroll
      for (int kk=0; kk<2; ++kk){
        #pragma unroll
        for (int fm=0;fm<4;fm++){
          #pragma unroll
          for (int fn=0;fn<4;fn++)
            acc[fm][fn] = __builtin_amdgcn_mfma_f32_16x16x32_bf16(
                af[fm][kk], *(const bf16x8*)&Br[fn*2+kk], acc[fm][fn], 0,0,0);
        }
      }
      __builtin_amdgcn_s_setprio(0);
    }
  }

  // epilogue: normalize each multivector; EPI==0 also emits fused Nq/Nk
  float hacc[2][2] = {{0.f,0.f},{0.f,0.f}};
  #pragma unroll
  for (int fn=0; fn<4; ++fn){
    const int c = col0 + wn*64 + fn*16 + lo;
    float s0=0.f, s1=0.f;
    #pragma unroll
    for (int r=0;r<4;r++){
      s0 += acc[0][fn][r]*acc[0][fn][r] + acc[1][fn][r]*acc[1][fn][r];
      s1 += acc[2][fn][r]*acc[2][fn][r] + acc[3][fn][r]*acc[3][fn][r];
    }
    s0 += __shfl_xor(s0,16); s0 += __shfl_xor(s0,32);
    s1 += __shfl_xor(s1,16); s1 += __shfl_xor(s1,32);
    if constexpr (EPI==0){
      hacc[fn>>1][0] += s0/(s0+1e-6f);
      hacc[fn>>1][1] += s1/(s1+1e-6f);
    }
    const float r0 = rsqrtf(s0+1e-6f), r1 = rsqrtf(s1+1e-6f);
    #pragma unroll
    for (int fm=0;fm<4;fm++){
      const float rs = (fm<2)? r0 : r1;
      const int bsg = (row0>>5) + wm*2 + (fm>>1);
      const int l0 = (fm&1)*16 + hi*4;
      float v0 = acc[fm][fn][0]*rs, v1 = acc[fm][fn][1]*rs, v2 = acc[fm][fn][2]*rs, v3 = acc[fm][fn][3]*rs;
      if constexpr (EPI==0){
        if (c < 256){ // fold SIG_DIAG into q
          if (sign_neg(l0+0,l0+0)) v0=-v0;
          if (sign_neg(l0+1,l0+1)) v1=-v1;
          if (sign_neg(l0+2,l0+2)) v2=-v2;
          if (sign_neg(l0+3,l0+3)) v3=-v3;
        }
        u16* dst = qkv + ((size_t)bsg*768 + c)*32 + l0;
        *(uint2*)dst = make_uint2(pack2(v0,v1), pack2(v2,v3));
      } else {
        float* dst = dout + ((size_t)bsg*256 + c)*32 + l0;
        *(float4*)dst = make_float4(v0,v1,v2,v3);
      }
    }
  }
  if constexpr (EPI==0){
    if (tn < 4){
      #pragma unroll
      for (int hs=0; hs<2; ++hs){
        #pragma unroll
        for (int p=0; p<2; ++p){
          float v = hacc[hs][p];
          v += __shfl_xor(v,1); v += __shfl_xor(v,2);
          v += __shfl_xor(v,4); v += __shfl_xor(v,8);
          hacc[hs][p] = v;
        }
      }
      if (lo==0 && hi==0){
        const int hb = ((col0&255)>>5) + wn*2;
        float* nd = (tn<2)? Nq : Nk;
        #pragma unroll
        for (int hs=0; hs<2; ++hs){
          #pragma unroll
          for (int p=0; p<2; ++p){
            const int bsf = (row0>>5) + wm*2 + p;
            const int b = bsf>>9, s = bsf&511;
            nd[((size_t)(b*8 + hb+hs))*512 + s] = hacc[hs][p];
          }
        }
      }
    }
  }
}

// ---------------- shared 128x128 MFMA tile engine (linear-row operands) -----------
DEVINL void mm_steps(const u16* Abase, int Astride, const u16* Bbase, int Bstride, int ksteps,
                     u16* Al, u16* Bl, f32x4 (&acc)[4][4], int lane, int wid){
  const int wm = wid>>1, wn = wid&1, lo = lane&15, hi = lane>>4;
  for (int s=0; s<ksteps; ++s){
    const int k0 = s*64;
    #pragma unroll
    for (int c=0;c<4;c++){
      const int gb = (wid*4+c)*64;
      const int idx = gb + lane;
      const int r = idx>>3, j = idx&7;
      const int sw = ((j^(r&7))*8);
      gload_lds16(Abase + (size_t)r*Astride + k0 + sw, Al + gb*8);
      gload_lds16(Bbase + (size_t)r*Bstride + k0 + sw, Bl + gb*8);
    }
    __syncthreads();
    #pragma unroll
    for (int kk=0; kk<2; ++kk){
      bf16x8 af[4], bfr[4];
      #pragma unroll
      for (int f=0;f<4;f++){
        const int ra = wm*64 + f*16 + lo;
        const int jc = kk*4 + hi;
        af[f] = *(const bf16x8*)(Al + ra*64 + ((jc^(ra&7))*8));
        const int rb = wn*64 + f*16 + lo;
        bfr[f] = *(const bf16x8*)(Bl + rb*64 + ((jc^(rb&7))*8));
      }
      #pragma unroll
      for (int fm=0;fm<4;fm++){
        #pragma unroll
        for (int fn=0;fn<4;fn++)
          acc[fm][fn] = __builtin_amdgcn_mfma_f32_16x16x32_bf16(af[fm], bfr[fn], acc[fm][fn], 0,0,0);
      }
    }
    __syncthreads();
  }
}

// ---------------- score: ss + gamma*bivector, write S1 f32 and S1T bf16 -----------
__global__ __launch_bounds__(256) void k_score(const u16* __restrict__ qkv, const float* __restrict__ Nq,
                                               const float* __restrict__ Nk, const float* __restrict__ gptr,
                                               float* __restrict__ S1, u16* __restrict__ S1T){
  __shared__ __align__(16) u16 Al[128*64];
  __shared__ __align__(16) u16 Bl[128*64];
  __shared__ __align__(16) u16 Tl[128*136];
  const int wg = blockIdx.x;
  const int bid = (wg&7)*32 + (wg>>3);
  const int bh = bid>>4, ti=(bid>>2)&3, tj=bid&3;
  const int b = bh>>3, h = bh&7;
  const int i0=ti*128, j0=tj*128;
  const int t=threadIdx.x, lane=t&63, wid=t>>6;
  const int wm=wid>>1, wn=wid&1, lo=lane&15, hi=lane>>4;
  f32x4 acc[4][4];
  #pragma unroll
  for(int a=0;a<4;a++){
    #pragma unroll
    for(int c=0;c<4;c++){ acc[a][c] = (f32x4){0.f,0.f,0.f,0.f}; }
  }
  const u16* Abase = qkv + ((size_t)(b*512+i0))*24576 + h*1024;
  const u16* Bbase = qkv + ((size_t)(b*512+j0))*24576 + 8192 + h*1024;
  mm_steps(Abase, 24576, Bbase, 24576, 16, Al, Bl, acc, lane, wid);
  const float gamma = *gptr;
  const float rhd = 0.17677669529663687f; // 1/sqrt(32)
  float nkv[4];
  #pragma unroll
  for (int fn=0;fn<4;fn++) nkv[fn] = Nk[bh*512 + j0 + wn*64 + fn*16 + lo];
  #pragma unroll
  for (int fm=0;fm<4;fm++){
    #pragma unroll
    for (int r=0;r<4;r++){
      const int iL = wm*64 + fm*16 + hi*4 + r;
      const float nq = Nq[bh*512 + i0 + iL];
      #pragma unroll
      for (int fn=0;fn<4;fn++){
        const int jL = wn*64 + fn*16 + lo;
        const float ss = acc[fm][fn][r];
        const float biv = sqrtf(fmaxf(nq*nkv[fn] - ss*ss, 0.f) + 1e-6f);
        const float sc = (ss + gamma*biv)*rhd;
        S1[((size_t)bh*512 + i0 + iL)*512 + j0 + jL] = sc;
        Tl[jL*136 + iL] = f2bf(sc);
      }
    }
  }
  __syncthreads();
  const int jj = t>>1, half = t&1;
  u16* dst = S1T + ((size_t)bh*512 + (j0+jj))*512 + i0 + half*64;
  #pragma unroll
  for (int q=0;q<8;q++)
    *(uint4*)(dst + q*8) = *(const uint4*)(Tl + jj*136 + half*64 + q*8);
}

// ---------------- row softmax (optionally masked), f32 in -> bf16 probs ----------
__global__ __launch_bounds__(256) void k_softmax(const float* __restrict__ S, const int* __restrict__ mask,
                                                 u16* __restrict__ P, int masked){
  __shared__ float redm[4], reds[4];
  const int row = blockIdx.x;          // bh*512 + i
  const int b = row>>12;
  const float* sp = S + (size_t)row*512;
  const int t = threadIdx.x, lane = t&63, wid = t>>6;
  float v0 = sp[t], v1 = sp[t+256];
  if (masked){
    if (mask[b*512 + t]   == 0) v0 = -1e9f;
    if (mask[b*512 + t+256] == 0) v1 = -1e9f;
  }
  float mx = fmaxf(v0,v1);
  #pragma unroll
  for (int o=1;o<64;o<<=1) mx = fmaxf(mx, __shfl_xor(mx,o));
  if (lane==0) redm[wid]=mx;
  __syncthreads();
  mx = fmaxf(fmaxf(redm[0],redm[1]), fmaxf(redm[2],redm[3]));
  const float e0 = __expf(v0-mx), e1 = __expf(v1-mx);
  float sm = e0+e1;
  #pragma unroll
  for (int o=1;o<64;o<<=1) sm += __shfl_xor(sm,o);
  if (lane==0) reds[wid]=sm;
  __syncthreads();
  sm = reds[0]+reds[1]+reds[2]+reds[3];
  const float inv = 1.f/sm;
  P[(size_t)row*512 + t]     = f2bf(e0*inv);
  P[(size_t)row*512 + t+256] = f2bf(e1*inv);
}

// ---------------- triangle update: S1 += 0.1 * P1 @ S1b (in place, f32) ----------
__global__ __launch_bounds__(256) void k_tri(const u16* __restrict__ P1, const u16* __restrict__ S1T,
                                             float* __restrict__ S1){
  __shared__ __align__(16) u16 Al[128*64];
  __shared__ __align__(16) u16 Bl[128*64];
  const int wg = blockIdx.x;
  const int bid = (wg&7)*32 + (wg>>3);
  const int bh = bid>>4, ti=(bid>>2)&3, tj=bid&3;
  const int i0=ti*128, j0=tj*128;
  const int t=threadIdx.x, lane=t&63, wid=t>>6;
  const int wm=wid>>1, wn=wid&1, lo=lane&15, hi=lane>>4;
  f32x4 acc[4][4];
  #pragma unroll
  for(int a=0;a<4;a++){
    #pragma unroll
    for(int c=0;c<4;c++){ acc[a][c] = (f32x4){0.f,0.f,0.f,0.f}; }
  }
  const u16* Abase = P1  + ((size_t)bh*512 + i0)*512;
  const u16* Bbase = S1T + ((size_t)bh*512 + j0)*512;
  mm_steps(Abase, 512, Bbase, 512, 8, Al, Bl, acc, lane, wid);
  #pragma unroll
  for (int fm=0;fm<4;fm++){
    #pragma unroll
    for (int r=0;r<4;r++){
      const int iL = wm*64 + fm*16 + hi*4 + r;
      #pragma unroll
      for (int fn=0;fn<4;fn++){
        const int jL = wn*64 + fn*16 + lo;
        const size_t idx = ((size_t)bh*512 + i0 + iL)*512 + j0 + jL;
        S1[idx] = S1[idx] + 0.1f*acc[fm][fn][r];
      }
    }
  }
}

// ---------------- transpose V to VT[bh][d][s] ------------------------------------
__global__ __launch_bounds__(256) void k_tr_v(const u16* __restrict__ qkv, u16* __restrict__ VT){
  __shared__ u16 tile[128*129];
  const int bid=blockIdx.x;
  const int bh = bid>>5, dch=(bid>>2)&7, sch=bid&3;
  const int b=bh>>3, h=bh&7;
  const int d0=dch*128, s0=sch*128;
  const int t=threadIdx.x;
  {
    const int r=t>>1, half=t&1;
    const u16* src = qkv + ((size_t)(b*512+s0+r))*24576 + 16384 + h*1024 + d0 + half*64;
    #pragma unroll
    for (int q=0;q<8;q++){
      uint4 v = *(const uint4*)(src + q*8);
      u16* dp = tile + r*129 + half*64 + q*8;
      dp[0]=(u16)(v.x&0xffffu); dp[1]=(u16)(v.x>>16); dp[2]=(u16)(v.y&0xffffu); dp[3]=(u16)(v.y>>16);
      dp[4]=(u16)(v.z&0xffffu); dp[5]=(u16)(v.z>>16); dp[6]=(u16)(v.w&0xffffu); dp[7]=(u16)(v.w>>16);
    }
  }
  __syncthreads();
  {
    const int rr=t>>1, half=t&1;
    u16* dst = VT + ((size_t)bh*1024 + d0+rr)*512 + s0 + half*64;
    #pragma unroll
    for (int q=0;q<4;q++){
      u32 w[8];
      #pragma unroll
      for (int e=0;e<8;e++){
        const int s = half*64 + q*16 + e*2;
        w[e] = (u32)tile[s*129+rr] | ((u32)tile[(s+1)*129+rr]<<16);
      }
      *(uint4*)(dst + q*16)     = make_uint4(w[0],w[1],w[2],w[3]);
      *(uint4*)(dst + q*16 + 8) = make_uint4(w[4],w[5],w[6],w[7]);
    }
  }
}

// ---------------- PV: out = P2 @ V, write transposed xt2[bs*32+l][e] bf16 --------
__global__ __launch_bounds__(256) void k_pv(const u16* __restrict__ P2, const u16* __restrict__ VT,
                                            u16* __restrict__ xt2){
  __shared__ __align__(16) u16 Al[128*64];
  __shared__ __align__(16) u16 Bl[128*64];
  __shared__ __align__(16) u16 Tl[128*136];
  const int wg = blockIdx.x;
  const int bid = (wg&7)*64 + (wg>>3);
  const int bh = bid>>5, ti=(bid>>3)&3, td=bid&7;
  const int b=bh>>3, h=bh&7;
  const int i0=ti*128, d0=td*128;
  const int t=threadIdx.x, lane=t&63, wid=t>>6;
  const int wm=wid>>1, wn=wid&1, lo=lane&15, hi=lane>>4;
  f32x4 acc[4][4];
  #pragma unroll
  for(int a=0;a<4;a++){
    #pragma unroll
    for(int c=0;c<4;c++){ acc[a][c] = (f32x4){0.f,0.f,0.f,0.f}; }
  }
  const u16* Abase = P2 + ((size_t)bh*512 + i0)*512;
  const u16* Bbase = VT + ((size_t)bh*1024 + d0)*512;
  mm_steps(Abase, 512, Bbase, 512, 8, Al, Bl, acc, lane, wid);
  #pragma unroll
  for (int fm=0;fm<4;fm++){
    #pragma unroll
    for (int r=0;r<4;r++){
      const int sL = wm*64 + fm*16 + hi*4 + r;
      #pragma unroll
      for (int fn=0;fn<4;fn++){
        const int dL = wn*64 + fn*16 + lo;
        Tl[sL*136 + dL] = f2bf(acc[fm][fn][r]);
      }
    }
  }
  __syncthreads();
  const int hd0 = td*4;
  #pragma unroll
  for (int u=0;u<16;u++){
    const int seg = t + u*256;
    const int sL = seg>>5, l = seg&31;
    const u16* tp = Tl + sL*136 + l;
    u32 w0 = (u32)tp[0]  | ((u32)tp[32]<<16);
    u32 w1 = (u32)tp[64] | ((u32)tp[96]<<16);
    u16* dst = xt2 + ((size_t)((b*512 + i0 + sL)*32 + l))*256 + h*32 + hd0;
    *(uint2*)dst = make_uint2(w0,w1);
  }
}

extern "C" void kernel_launch(void* const* d_in, const int* in_sizes, int n_in,
                              void* d_out, int out_size, void* d_ws, size_t ws_size,
                              hipStream_t stream) {
  const float* x  = (const float*)d_in[0];
  const float* wq = (const float*)d_in[1];
  const float* wk = (const float*)d_in[2];
  const float* wv = (const float*)d_in[3];
  const float* wo = (const float*)d_in[4];
  const float* gamma = (const float*)d_in[5];
  const int*   mask  = (const int*)d_in[6];
  float* out = (float*)d_out;

  char* ws = (char*)d_ws;
  size_t off = 0;
  auto alloc = [&](size_t n){ char* p = ws + off; off += (n + 255) & ~(size_t)255; return p; };
  u16*  xt  = (u16*) alloc(16777216);   // [32768][256] bf16
  u16*  wT3 = (u16*) alloc(16777216);   // [4][32][4][16][2][64][8] bf16 fragment-order
  u16*  qkv = (u16*) alloc(50331648);   // [1024][768][32] bf16
  float* Nq = (float*)alloc(32768);
  float* Nk = (float*)alloc(32768);
  float* S1 = (float*)alloc(16777216);  // [16][512][512] f32
  u16*  S1T = (u16*) alloc(8388608);    // [16][512][512] bf16 (transposed)
  u16*  P2  = (u16*) alloc(8388608);
  u16*  VT  = (u16*) alloc(16777216);   // [16][1024][512] bf16
  u16*  P1  = xt;                       // alias: xt dead after gemm<0>; P1 dead before k_pv writes xt2
  u16*  xt2 = xt;                       // alias: reuse xt region for attention output

  k_tr_x<<<1024, 256, 0, stream>>>(x, xt);
  k_tr_w<<<1024, 256, 0, stream>>>(wq, wk, wv, wo, wT3);
  k_geo_gemm<0><<<1536, 256, 0, stream>>>(xt, wT3, qkv, nullptr, Nq, Nk);
  k_score<<<256, 256, 0, stream>>>(qkv, Nq, Nk, gamma, S1, S1T);
  k_softmax<<<8192, 256, 0, stream>>>(S1, mask, P1, 0);
  k_tri<<<256, 256, 0, stream>>>(P1, S1T, S1);
  k_softmax<<<8192, 256, 0, stream>>>(S1, mask, P2, 1);
  k_tr_v<<<512, 256, 0, stream>>>(qkv, VT);
  k_pv<<<512, 256, 0, stream>>>(P2, VT, xt2);
  k_geo_gemm<1><<<512, 256, 0, stream>>>(xt2, wT3, nullptr, out, nullptr, nullptr);
}

// Round 10
// 533.029 us; speedup vs baseline: 2.0341x; 1.0242x over previous
//
#include <hip/hip_runtime.h>
#include <stdint.h>

typedef unsigned short u16;
typedef unsigned int u32;
typedef __attribute__((ext_vector_type(8))) __bf16 bf16x8;
typedef __attribute__((ext_vector_type(4))) float f32x4;

#define DEVINL __device__ __forceinline__

DEVINL float bf2f(u16 u){ union{u32 i; float f;} c; c.i = ((u32)u)<<16; return c.f; }
DEVINL u16 f2bf(float f){ union{float f; u32 i;} c; c.f=f; u32 u=c.i; return (u16)((u + 0x7fffu + ((u>>16)&1u))>>16); }
DEVINL u32 pack2(float a, float b){ return (u32)f2bf(a) | ((u32)f2bf(b)<<16); }
DEVINL float sq2(u32 u){ float a = bf2f((u16)(u&0xffffu)), b = bf2f((u16)(u>>16)); return a*a + b*b; }

// parity of sign(e_a * e_b) in Cl(4,1): reorder swaps + metric (e4^2 = -1)
DEVINL int sign_neg(int a, int b){
  int s = __popc((a>>1)&b) + __popc((a>>2)&b) + __popc((a>>3)&b) + __popc((a>>4)&b) + ((a&b)>>4);
  return s & 1;
}

constexpr u32 sgn_mask(int m){
  u32 r = 0;
  for (int n=0;n<32;n++){
    int s = __builtin_popcount((m>>1)&n) + __builtin_popcount((m>>2)&n)
          + __builtin_popcount((m>>3)&n) + __builtin_popcount((m>>4)&n) + ((m&n)>>4);
    r |= (u32)(s&1) << n;
  }
  return r;
}
__device__ __constant__ u32 SGNC[32] = {
  sgn_mask(0), sgn_mask(1), sgn_mask(2), sgn_mask(3), sgn_mask(4), sgn_mask(5), sgn_mask(6), sgn_mask(7),
  sgn_mask(8), sgn_mask(9), sgn_mask(10),sgn_mask(11),sgn_mask(12),sgn_mask(13),sgn_mask(14),sgn_mask(15),
  sgn_mask(16),sgn_mask(17),sgn_mask(18),sgn_mask(19),sgn_mask(20),sgn_mask(21),sgn_mask(22),sgn_mask(23),
  sgn_mask(24),sgn_mask(25),sgn_mask(26),sgn_mask(27),sgn_mask(28),sgn_mask(29),sgn_mask(30),sgn_mask(31)};

DEVINL void gload_lds16(const void* g, void* l){
  __builtin_amdgcn_global_load_lds(
    (const __attribute__((address_space(1))) void*)g,
    (__attribute__((address_space(3))) void*)l, 16, 0, 0);
}

// ---------------- transpose x: [bs][i=256][n=32] f32 -> xt [bs*32+n][i] bf16 -----
__global__ __launch_bounds__(256) void k_tr_x(const float* __restrict__ x, u16* __restrict__ xt){
  __shared__ float tile[256][33];
  const int bs = blockIdx.x, t = threadIdx.x;
  const float* xp = x + (size_t)bs*8192 + t*32;
  #pragma unroll
  for (int n=0;n<32;n+=4){
    float4 v = *(const float4*)(xp + n);
    tile[t][n]=v.x; tile[t][n+1]=v.y; tile[t][n+2]=v.z; tile[t][n+3]=v.w;
  }
  __syncthreads();
  const int n = t>>3, i0 = (t&7)*32;
  u16* dst = xt + ((size_t)bs*32 + n)*256 + i0;
  #pragma unroll
  for (int q=0;q<4;q++){
    u32 w0 = pack2(tile[i0+q*8+0][n], tile[i0+q*8+1][n]);
    u32 w1 = pack2(tile[i0+q*8+2][n], tile[i0+q*8+3][n]);
    u32 w2 = pack2(tile[i0+q*8+4][n], tile[i0+q*8+5][n]);
    u32 w3 = pack2(tile[i0+q*8+6][n], tile[i0+q*8+7][n]);
    *(uint4*)(dst + q*8) = make_uint4(w0,w1,w2,w3);
  }
}

// ---------------- transpose w into MFMA-fragment order -----------------------------
// wT3[wsel][m][q][o_blk][kk][lane][e]: lane = (o&15) + k8*16, i = q*64+kk*32+k8*8+e
__global__ __launch_bounds__(256) void k_tr_w(const float* __restrict__ wq, const float* __restrict__ wk,
                                              const float* __restrict__ wv, const float* __restrict__ wo,
                                              u16* __restrict__ wT3){
  __shared__ float tile[256][33];
  const int bid = blockIdx.x, t = threadIdx.x;
  const int wsel = bid>>8, o = bid&255;
  const float* w = wsel==0?wq: wsel==1?wk: wsel==2?wv: wo;
  const float* wp = w + ((size_t)o*256 + t)*32;
  #pragma unroll
  for (int m=0;m<32;m+=4){
    float4 v = *(const float4*)(wp + m);
    tile[t][m]=v.x; tile[t][m+1]=v.y; tile[t][m+2]=v.z; tile[t][m+3]=v.w;
  }
  __syncthreads();
  const int m = t>>3, sub = t&7;
  const int q = sub>>1, kk = sub&1;
  const int c = o&15, obk = o>>4;
  const size_t base = (((((size_t)wsel*32 + m)*4 + q)*16 + obk)*2 + kk)*512;
  #pragma unroll
  for (int k8=0;k8<4;k8++){
    const int i0 = sub*32 + k8*8;
    u32 w0 = pack2(tile[i0+0][m], tile[i0+1][m]);
    u32 w1 = pack2(tile[i0+2][m], tile[i0+3][m]);
    u32 w2 = pack2(tile[i0+4][m], tile[i0+5][m]);
    u32 w3 = pack2(tile[i0+6][m], tile[i0+7][m]);
    *(uint4*)(wT3 + base + (size_t)(c + k8*16)*8) = make_uint4(w0,w1,w2,w3);
  }
}

// geo GEMM: out[bs,o,l] = sum_{m,i} xt[bs,l^m,i]*sign(m,l^m)*wT[m][o][i]
// 128x128 tile, 4 waves (2x2). A i-quarter LDS-resident in DUAL-SIGN form
// (+A at [0,16KB), -A at [16KB,32KB)); per-m blade perm+sign at fragment read
// is pure ADDRESSING (XOR-delta + sign bit -> +16KB offset), zero data VALU.
// B streamed global->registers from fragment-ordered wT3 (coalesced dwordx4,
// L2-resident per XCD). NO barriers / NO LDS traffic for B in the m-loop.
template<int EPI>
__global__ __launch_bounds__(256) void k_geo_gemm(const u16* __restrict__ xt, const u16* __restrict__ wT3,
                                                  u16* __restrict__ qkv, float* __restrict__ dout,
                                                  float* __restrict__ Nq, float* __restrict__ Nk){
  constexpr int NT = (EPI==0)?6:2;
  constexpr int NWG = 256*NT;
  __shared__ __align__(16) u16 Apan[2*128*64];   // 32 KB: +A | -A
  const int wg = blockIdx.x;
  const int bid = (wg&7)*(NWG/8) + (wg>>3);      // bijective XCD chunking, tn-major
  const int tn = bid >> 8;
  const int tm = bid & 255;
  const int row0 = tm*128, col0 = tn*128;
  const int wsel = (EPI==0)? (col0>>8) : 3;
  const int o0   = (EPI==0)? (col0&255) : col0;
  const u16* Wp = wT3 + (size_t)wsel*2097152;    // panel base (u16)
  const int t = threadIdx.x, lane = t&63, wid = t>>6;
  const int wm = wid>>1, wn = wid&1, lo = lane&15, hi = lane>>4;

  // A base byte-offsets (m=0) and per-lane sign words
  int baseA[4][2]; u32 sgnw[4];
  #pragma unroll
  for (int f=0; f<4; ++f){
    const int ra = wm*64 + f*16 + lo;
    #pragma unroll
    for (int kk=0; kk<2; ++kk)
      baseA[f][kk] = ra*128 + (((kk*4+hi) ^ (lo&7))*16);
    const int rl = ra & 31;
    u32 sw = 0;
    for (int m=0;m<32;m++) sw |= ((SGNC[m] >> ((rl^m)&31)) & 1u) << m;
    sgnw[f] = sw;
  }
  // B fragment offsets (u16 units) within a (m,q) super-block
  int boff[4][2];
  #pragma unroll
  for (int fn=0; fn<4; ++fn){
    const int ob = (o0>>4) + wn*4 + fn;
    #pragma unroll
    for (int kk=0; kk<2; ++kk)
      boff[fn][kk] = (ob*2+kk)*512 + lane*8;
  }

  f32x4 acc[4][4];
  #pragma unroll
  for(int a=0;a<4;a++){
    #pragma unroll
    for(int b=0;b<4;b++){ acc[a][b] = (f32x4){0.f,0.f,0.f,0.f}; }
  }
  const char* Ab = (const char*)Apan;

  for (int q=0; q<4; ++q){
    __syncthreads();                 // previous quarter fully consumed
    #pragma unroll
    for (int c=0;c<4;c++){
      const int base = (wid*4+c)*64;
      const int idx = base + lane;
      const int rr = idx>>3, g = idx&7;
      gload_lds16(xt + (size_t)(row0+rr)*256 + q*64 + ((g^(rr&7))*8), Apan + base*8);
    }
    __syncthreads();                 // drain: +A quarter visible
    // build negated copy at +16KB (LDS->LDS, sign-bit XOR)
    #pragma unroll
    for (int c=0;c<4;c++){
      const int idx = c*256 + t;
      uint4 v = *(const uint4*)(Apan + idx*8);
      v.x^=0x80008000u; v.y^=0x80008000u; v.z^=0x80008000u; v.w^=0x80008000u;
      *(uint4*)(Apan + 8192 + idx*8) = v;
    }
    __syncthreads();                 // -A visible
    const u16* Wq = Wp + (size_t)q*16384;
    for (int m=0; m<32; ++m){
      const u16* Wm = Wq + (size_t)m*65536;
      // issue B fragment loads (coalesced dwordx4; covered by A-side work below)
      uint4 Br[8];
      #pragma unroll
      for (int fn=0; fn<4; ++fn){
        #pragma unroll
        for (int kk=0; kk<2; ++kk)
          Br[fn*2+kk] = *(const uint4*)(Wm + boff[fn][kk]);
      }
      // A fragments: XOR-delta addressing; sign = +16KB panel select
      const int dlt = (m<<7) | ((m&7)<<4);
      bf16x8 af[4][2];
      #pragma unroll
      for (int f=0; f<4; ++f){
        const int soff = (int)((sgnw[f] >> m) & 1u) << 14;
        #pragma unroll
        for (int kk=0; kk<2; ++kk)
          af[f][kk] = *(const bf16x8*)(Ab + ((baseA[f][kk] ^ dlt) | soff));
      }
      __builtin_amdgcn_s_setprio(1);
      #pragma unroll
      for (int kk=0; kk<2; ++kk){
        #pragma unroll
        for (int fm=0;fm<4;fm++){
          #pragma unroll
          for (int fn=0;fn<4;fn++)
            acc[fm][fn] = __builtin_amdgcn_mfma_f32_16x16x32_bf16(
                af[fm][kk], *(const bf16x8*)&Br[fn*2+kk], acc[fm][fn], 0,0,0);
        }
      }
      __builtin_amdgcn_s_setprio(0);
    }
  }

  // epilogue: normalize each multivector; EPI==0 also emits fused Nq/Nk
  float hacc[2][2] = {{0.f,0.f},{0.f,0.f}};
  #pragma unroll
  for (int fn=0; fn<4; ++fn){
    const int c = col0 + wn*64 + fn*16 + lo;
    float s0=0.f, s1=0.f;
    #pragma unroll
    for (int r=0;r<4;r++){
      s0 += acc[0][fn][r]*acc[0][fn][r] + acc[1][fn][r]*acc[1][fn][r];
      s1 += acc[2][fn][r]*acc[2][fn][r] + acc[3][fn][r]*acc[3][fn][r];
    }
    s0 += __shfl_xor(s0,16); s0 += __shfl_xor(s0,32);
    s1 += __shfl_xor(s1,16); s1 += __shfl_xor(s1,32);
    if constexpr (EPI==0){
      hacc[fn>>1][0] += s0/(s0+1e-6f);
      hacc[fn>>1][1] += s1/(s1+1e-6f);
    }
    const float r0 = rsqrtf(s0+1e-6f), r1 = rsqrtf(s1+1e-6f);
    #pragma unroll
    for (int fm=0;fm<4;fm++){
      const float rs = (fm<2)? r0 : r1;
      const int bsg = (row0>>5) + wm*2 + (fm>>1);
      const int l0 = (fm&1)*16 + hi*4;
      float v0 = acc[fm][fn][0]*rs, v1 = acc[fm][fn][1]*rs, v2 = acc[fm][fn][2]*rs, v3 = acc[fm][fn][3]*rs;
      if constexpr (EPI==0){
        if (c < 256){ // fold SIG_DIAG into q
          if (sign_neg(l0+0,l0+0)) v0=-v0;
          if (sign_neg(l0+1,l0+1)) v1=-v1;
          if (sign_neg(l0+2,l0+2)) v2=-v2;
          if (sign_neg(l0+3,l0+3)) v3=-v3;
        }
        u16* dst = qkv + ((size_t)bsg*768 + c)*32 + l0;
        *(uint2*)dst = make_uint2(pack2(v0,v1), pack2(v2,v3));
      } else {
        float* dst = dout + ((size_t)bsg*256 + c)*32 + l0;
        *(float4*)dst = make_float4(v0,v1,v2,v3);
      }
    }
  }
  if constexpr (EPI==0){
    if (tn < 4){
      #pragma unroll
      for (int hs=0; hs<2; ++hs){
        #pragma unroll
        for (int p=0; p<2; ++p){
          float v = hacc[hs][p];
          v += __shfl_xor(v,1); v += __shfl_xor(v,2);
          v += __shfl_xor(v,4); v += __shfl_xor(v,8);
          hacc[hs][p] = v;
        }
      }
      if (lo==0 && hi==0){
        const int hb = ((col0&255)>>5) + wn*2;
        float* nd = (tn<2)? Nq : Nk;
        #pragma unroll
        for (int hs=0; hs<2; ++hs){
          #pragma unroll
          for (int p=0; p<2; ++p){
            const int bsf = (row0>>5) + wm*2 + p;
            const int b = bsf>>9, s = bsf&511;
            nd[((size_t)(b*8 + hb+hs))*512 + s] = hacc[hs][p];
          }
        }
      }
    }
  }
}

// ---------------- shared 128x128 MFMA tile engine (linear-row operands) -----------
DEVINL void mm_steps(const u16* Abase, int Astride, const u16* Bbase, int Bstride, int ksteps,
                     u16* Al, u16* Bl, f32x4 (&acc)[4][4], int lane, int wid){
  const int wm = wid>>1, wn = wid&1, lo = lane&15, hi = lane>>4;
  for (int s=0; s<ksteps; ++s){
    const int k0 = s*64;
    #pragma unroll
    for (int c=0;c<4;c++){
      const int gb = (wid*4+c)*64;
      const int idx = gb + lane;
      const int r = idx>>3, j = idx&7;
      const int sw = ((j^(r&7))*8);
      gload_lds16(Abase + (size_t)r*Astride + k0 + sw, Al + gb*8);
      gload_lds16(Bbase + (size_t)r*Bstride + k0 + sw, Bl + gb*8);
    }
    __syncthreads();
    #pragma unroll
    for (int kk=0; kk<2; ++kk){
      bf16x8 af[4], bfr[4];
      #pragma unroll
      for (int f=0;f<4;f++){
        const int ra = wm*64 + f*16 + lo;
        const int jc = kk*4 + hi;
        af[f] = *(const bf16x8*)(Al + ra*64 + ((jc^(ra&7))*8));
        const int rb = wn*64 + f*16 + lo;
        bfr[f] = *(const bf16x8*)(Bl + rb*64 + ((jc^(rb&7))*8));
      }
      #pragma unroll
      for (int fm=0;fm<4;fm++){
        #pragma unroll
        for (int fn=0;fn<4;fn++)
          acc[fm][fn] = __builtin_amdgcn_mfma_f32_16x16x32_bf16(af[fm], bfr[fn], acc[fm][fn], 0,0,0);
      }
    }
    __syncthreads();
  }
}

// ---------------- score: ss + gamma*bivector, write S1 f32 and S1T bf16 -----------
__global__ __launch_bounds__(256) void k_score(const u16* __restrict__ qkv, const float* __restrict__ Nq,
                                               const float* __restrict__ Nk, const float* __restrict__ gptr,
                                               float* __restrict__ S1, u16* __restrict__ S1T){
  __shared__ __align__(16) u16 Al[128*64];
  __shared__ __align__(16) u16 Bl[128*64];
  __shared__ __align__(16) u16 Tl[128*136];
  const int wg = blockIdx.x;
  const int bid = (wg&7)*32 + (wg>>3);
  const int bh = bid>>4, ti=(bid>>2)&3, tj=bid&3;
  const int b = bh>>3, h = bh&7;
  const int i0=ti*128, j0=tj*128;
  const int t=threadIdx.x, lane=t&63, wid=t>>6;
  const int wm=wid>>1, wn=wid&1, lo=lane&15, hi=lane>>4;
  f32x4 acc[4][4];
  #pragma unroll
  for(int a=0;a<4;a++){
    #pragma unroll
    for(int c=0;c<4;c++){ acc[a][c] = (f32x4){0.f,0.f,0.f,0.f}; }
  }
  const u16* Abase = qkv + ((size_t)(b*512+i0))*24576 + h*1024;
  const u16* Bbase = qkv + ((size_t)(b*512+j0))*24576 + 8192 + h*1024;
  mm_steps(Abase, 24576, Bbase, 24576, 16, Al, Bl, acc, lane, wid);
  const float gamma = *gptr;
  const float rhd = 0.17677669529663687f; // 1/sqrt(32)
  float nkv[4];
  #pragma unroll
  for (int fn=0;fn<4;fn++) nkv[fn] = Nk[bh*512 + j0 + wn*64 + fn*16 + lo];
  #pragma unroll
  for (int fm=0;fm<4;fm++){
    #pragma unroll
    for (int r=0;r<4;r++){
      const int iL = wm*64 + fm*16 + hi*4 + r;
      const float nq = Nq[bh*512 + i0 + iL];
      #pragma unroll
      for (int fn=0;fn<4;fn++){
        const int jL = wn*64 + fn*16 + lo;
        const float ss = acc[fm][fn][r];
        const float biv = sqrtf(fmaxf(nq*nkv[fn] - ss*ss, 0.f) + 1e-6f);
        const float sc = (ss + gamma*biv)*rhd;
        S1[((size_t)bh*512 + i0 + iL)*512 + j0 + jL] = sc;
        Tl[jL*136 + iL] = f2bf(sc);
      }
    }
  }
  __syncthreads();
  const int jj = t>>1, half = t&1;
  u16* dst = S1T + ((size_t)bh*512 + (j0+jj))*512 + i0 + half*64;
  #pragma unroll
  for (int q=0;q<8;q++)
    *(uint4*)(dst + q*8) = *(const uint4*)(Tl + jj*136 + half*64 + q*8);
}

// ---------------- row softmax, wave-per-row (optionally masked) -------------------
__global__ __launch_bounds__(256) void k_softmax(const float* __restrict__ S, const int* __restrict__ mask,
                                                 u16* __restrict__ P, int masked){
  const int t = threadIdx.x, lane = t&63, wid = t>>6;
  const int row = blockIdx.x*4 + wid;   // bh*512 + i
  const int b = row>>12;
  const float* sp = S + (size_t)row*512;
  float4 a = *(const float4*)(sp + lane*4);
  float4 c = *(const float4*)(sp + 256 + lane*4);
  if (masked){
    const int* mp = mask + b*512;
    int4 ma = *(const int4*)(mp + lane*4);
    int4 mc = *(const int4*)(mp + 256 + lane*4);
    if (ma.x==0) a.x=-1e9f; if (ma.y==0) a.y=-1e9f; if (ma.z==0) a.z=-1e9f; if (ma.w==0) a.w=-1e9f;
    if (mc.x==0) c.x=-1e9f; if (mc.y==0) c.y=-1e9f; if (mc.z==0) c.z=-1e9f; if (mc.w==0) c.w=-1e9f;
  }
  float mx = fmaxf(fmaxf(fmaxf(a.x,a.y),fmaxf(a.z,a.w)), fmaxf(fmaxf(c.x,c.y),fmaxf(c.z,c.w)));
  #pragma unroll
  for (int o=1;o<64;o<<=1) mx = fmaxf(mx, __shfl_xor(mx,o));
  const float e0=__expf(a.x-mx), e1=__expf(a.y-mx), e2=__expf(a.z-mx), e3=__expf(a.w-mx);
  const float e4=__expf(c.x-mx), e5=__expf(c.y-mx), e6=__expf(c.z-mx), e7=__expf(c.w-mx);
  float sm = (e0+e1)+(e2+e3)+(e4+e5)+(e6+e7);
  #pragma unroll
  for (int o=1;o<64;o<<=1) sm += __shfl_xor(sm,o);
  const float inv = 1.f/sm;
  u16* pp = P + (size_t)row*512;
  *(uint2*)(pp + lane*4)       = make_uint2(pack2(e0*inv,e1*inv), pack2(e2*inv,e3*inv));
  *(uint2*)(pp + 256 + lane*4) = make_uint2(pack2(e4*inv,e5*inv), pack2(e6*inv,e7*inv));
}

// ---------------- triangle update: S1 += 0.1 * P1 @ S1b (in place, f32) ----------
__global__ __launch_bounds__(256) void k_tri(const u16* __restrict__ P1, const u16* __restrict__ S1T,
                                             float* __restrict__ S1){
  __shared__ __align__(16) u16 Al[128*64];
  __shared__ __align__(16) u16 Bl[128*64];
  const int wg = blockIdx.x;
  const int bid = (wg&7)*32 + (wg>>3);
  const int bh = bid>>4, ti=(bid>>2)&3, tj=bid&3;
  const int i0=ti*128, j0=tj*128;
  const int t=threadIdx.x, lane=t&63, wid=t>>6;
  const int wm=wid>>1, wn=wid&1, lo=lane&15, hi=lane>>4;
  f32x4 acc[4][4];
  #pragma unroll
  for(int a=0;a<4;a++){
    #pragma unroll
    for(int c=0;c<4;c++){ acc[a][c] = (f32x4){0.f,0.f,0.f,0.f}; }
  }
  const u16* Abase = P1  + ((size_t)bh*512 + i0)*512;
  const u16* Bbase = S1T + ((size_t)bh*512 + j0)*512;
  mm_steps(Abase, 512, Bbase, 512, 8, Al, Bl, acc, lane, wid);
  #pragma unroll
  for (int fm=0;fm<4;fm++){
    #pragma unroll
    for (int r=0;r<4;r++){
      const int iL = wm*64 + fm*16 + hi*4 + r;
      #pragma unroll
      for (int fn=0;fn<4;fn++){
        const int jL = wn*64 + fn*16 + lo;
        const size_t idx = ((size_t)bh*512 + i0 + iL)*512 + j0 + jL;
        S1[idx] = S1[idx] + 0.1f*acc[fm][fn][r];
      }
    }
  }
}

// ---------------- transpose V to VT[bh][d][s] ------------------------------------
__global__ __launch_bounds__(256) void k_tr_v(const u16* __restrict__ qkv, u16* __restrict__ VT){
  __shared__ u16 tile[128*129];
  const int bid=blockIdx.x;
  const int bh = bid>>5, dch=(bid>>2)&7, sch=bid&3;
  const int b=bh>>3, h=bh&7;
  const int d0=dch*128, s0=sch*128;
  const int t=threadIdx.x;
  {
    const int r=t>>1, half=t&1;
    const u16* src = qkv + ((size_t)(b*512+s0+r))*24576 + 16384 + h*1024 + d0 + half*64;
    #pragma unroll
    for (int q=0;q<8;q++){
      uint4 v = *(const uint4*)(src + q*8);
      u16* dp = tile + r*129 + half*64 + q*8;
      dp[0]=(u16)(v.x&0xffffu); dp[1]=(u16)(v.x>>16); dp[2]=(u16)(v.y&0xffffu); dp[3]=(u16)(v.y>>16);
      dp[4]=(u16)(v.z&0xffffu); dp[5]=(u16)(v.z>>16); dp[6]=(u16)(v.w&0xffffu); dp[7]=(u16)(v.w>>16);
    }
  }
  __syncthreads();
  {
    const int rr=t>>1, half=t&1;
    u16* dst = VT + ((size_t)bh*1024 + d0+rr)*512 + s0 + half*64;
    #pragma unroll
    for (int q=0;q<4;q++){
      u32 w[8];
      #pragma unroll
      for (int e=0;e<8;e++){
        const int s = half*64 + q*16 + e*2;
        w[e] = (u32)tile[s*129+rr] | ((u32)tile[(s+1)*129+rr]<<16);
      }
      *(uint4*)(dst + q*16)     = make_uint4(w[0],w[1],w[2],w[3]);
      *(uint4*)(dst + q*16 + 8) = make_uint4(w[4],w[5],w[6],w[7]);
    }
  }
}

// ---------------- PV: out = P2 @ V, write transposed xt2[bs*32+l][e] bf16 --------
__global__ __launch_bounds__(256) void k_pv(const u16* __restrict__ P2, const u16* __restrict__ VT,
                                            u16* __restrict__ xt2){
  __shared__ __align__(16) u16 Al[128*64];
  __shared__ __align__(16) u16 Bl[128*64];
  __shared__ __align__(16) u16 Tl[128*136];
  const int wg = blockIdx.x;
  const int bid = (wg&7)*64 + (wg>>3);
  const int bh = bid>>5, ti=(bid>>3)&3, td=bid&7;
  const int b=bh>>3, h=bh&7;
  const int i0=ti*128, d0=td*128;
  const int t=threadIdx.x, lane=t&63, wid=t>>6;
  const int wm=wid>>1, wn=wid&1, lo=lane&15, hi=lane>>4;
  f32x4 acc[4][4];
  #pragma unroll
  for(int a=0;a<4;a++){
    #pragma unroll
    for(int c=0;c<4;c++){ acc[a][c] = (f32x4){0.f,0.f,0.f,0.f}; }
  }
  const u16* Abase = P2 + ((size_t)bh*512 + i0)*512;
  const u16* Bbase = VT + ((size_t)bh*1024 + d0)*512;
  mm_steps(Abase, 512, Bbase, 512, 8, Al, Bl, acc, lane, wid);
  #pragma unroll
  for (int fm=0;fm<4;fm++){
    #pragma unroll
    for (int r=0;r<4;r++){
      const int sL = wm*64 + fm*16 + hi*4 + r;
      #pragma unroll
      for (int fn=0;fn<4;fn++){
        const int dL = wn*64 + fn*16 + lo;
        Tl[sL*136 + dL] = f2bf(acc[fm][fn][r]);
      }
    }
  }
  __syncthreads();
  const int hd0 = td*4;
  #pragma unroll
  for (int u=0;u<16;u++){
    const int seg = t + u*256;
    const int sL = seg>>5, l = seg&31;
    const u16* tp = Tl + sL*136 + l;
    u32 w0 = (u32)tp[0]  | ((u32)tp[32]<<16);
    u32 w1 = (u32)tp[64] | ((u32)tp[96]<<16);
    u16* dst = xt2 + ((size_t)((b*512 + i0 + sL)*32 + l))*256 + h*32 + hd0;
    *(uint2*)dst = make_uint2(w0,w1);
  }
}

extern "C" void kernel_launch(void* const* d_in, const int* in_sizes, int n_in,
                              void* d_out, int out_size, void* d_ws, size_t ws_size,
                              hipStream_t stream) {
  const float* x  = (const float*)d_in[0];
  const float* wq = (const float*)d_in[1];
  const float* wk = (const float*)d_in[2];
  const float* wv = (const float*)d_in[3];
  const float* wo = (const float*)d_in[4];
  const float* gamma = (const float*)d_in[5];
  const int*   mask  = (const int*)d_in[6];
  float* out = (float*)d_out;

  char* ws = (char*)d_ws;
  size_t off = 0;
  auto alloc = [&](size_t n){ char* p = ws + off; off += (n + 255) & ~(size_t)255; return p; };
  u16*  xt  = (u16*) alloc(16777216);   // [32768][256] bf16
  u16*  wT3 = (u16*) alloc(16777216);   // [4][32][4][16][2][64][8] bf16 fragment-order
  u16*  qkv = (u16*) alloc(50331648);   // [1024][768][32] bf16
  float* Nq = (float*)alloc(32768);
  float* Nk = (float*)alloc(32768);
  float* S1 = (float*)alloc(16777216);  // [16][512][512] f32
  u16*  S1T = (u16*) alloc(8388608);    // [16][512][512] bf16 (transposed)
  u16*  P2  = (u16*) alloc(8388608);
  u16*  VT  = (u16*) alloc(16777216);   // [16][1024][512] bf16
  u16*  P1  = xt;                       // alias: xt dead after gemm<0>; P1 dead before k_pv writes xt2
  u16*  xt2 = xt;                       // alias: reuse xt region for attention output

  k_tr_x<<<1024, 256, 0, stream>>>(x, xt);
  k_tr_w<<<1024, 256, 0, stream>>>(wq, wk, wv, wo, wT3);
  k_geo_gemm<0><<<1536, 256, 0, stream>>>(xt, wT3, qkv, nullptr, Nq, Nk);
  k_score<<<256, 256, 0, stream>>>(qkv, Nq, Nk, gamma, S1, S1T);
  k_softmax<<<2048, 256, 0, stream>>>(S1, mask, P1, 0);
  k_tri<<<256, 256, 0, stream>>>(P1, S1T, S1);
  k_softmax<<<2048, 256, 0, stream>>>(S1, mask, P2, 1);
  k_tr_v<<<512, 256, 0, stream>>>(qkv, VT);
  k_pv<<<512, 256, 0, stream>>>(P2, VT, xt2);
  k_geo_gemm<1><<<512, 256, 0, stream>>>(xt2, wT3, nullptr, out, nullptr, nullptr);
}